// Round 3
// baseline (942.463 us; speedup 1.0000x reference)
//
#include <hip/hip_runtime.h>

#define SH 68            // padded LDS row stride (floats) for fp32 prep kernels
#define DT_C 0.1f

typedef short bfrag __attribute__((ext_vector_type(8)));   // 8 bf16 (4 VGPR)
typedef float f32x4 __attribute__((ext_vector_type(4)));

union FU { bfrag v; unsigned short s[8]; uint4 q; };

__device__ __forceinline__ unsigned short bf16_rn(float x) {
  union { float f; unsigned u; } v; v.f = x;
  unsigned r = v.u + 0x7fffu + ((v.u >> 16) & 1u);
  return (unsigned short)(r >> 16);
}
__device__ __forceinline__ float bf16_tof(unsigned short h) {
  union { unsigned u; float f; } v; v.u = ((unsigned)h) << 16; return v.f;
}
__device__ __forceinline__ float tanh_f(float x) {
  return 1.0f - 2.0f / (__expf(2.0f * x) + 1.0f);
}
__device__ __forceinline__ void unpk(uint4 q0, uint4 q1, FU& h, FU& l) {
  unsigned u[8] = {q0.x, q0.y, q0.z, q0.w, q1.x, q1.y, q1.z, q1.w};
  #pragma unroll
  for (int i = 0; i < 8; ++i) {
    h.s[i] = (unsigned short)(u[i] & 0xffffu);
    l.s[i] = (unsigned short)(u[i] >> 16);
  }
}

// ---- fp32 4x4-block 64-K matmul helper (A stride SH; acc += A[n0..][*] * B[*][e0..]) ----
__device__ __forceinline__ void mm16(const float* __restrict__ A,
                                     const float* __restrict__ B, int sb,
                                     float acc[4][4], int n0, int e0) {
  #pragma unroll 2
  for (int k = 0; k < 64; ++k) {
    float a0 = A[(n0+0)*SH+k];
    float a1 = A[(n0+1)*SH+k];
    float a2 = A[(n0+2)*SH+k];
    float a3 = A[(n0+3)*SH+k];
    const float4 bv = *(const float4*)(B + k*sb + e0);
    acc[0][0]+=a0*bv.x; acc[0][1]+=a0*bv.y; acc[0][2]+=a0*bv.z; acc[0][3]+=a0*bv.w;
    acc[1][0]+=a1*bv.x; acc[1][1]+=a1*bv.y; acc[1][2]+=a1*bv.z; acc[1][3]+=a1*bv.w;
    acc[2][0]+=a2*bv.x; acc[2][1]+=a2*bv.y; acc[2][2]+=a2*bv.z; acc[2][3]+=a2*bv.w;
    acc[3][0]+=a3*bv.x; acc[3][1]+=a3*bv.y; acc[3][2]+=a3*bv.z; acc[3][3]+=a3*bv.w;
  }
}

// ---- conv1: [512,3,64,64] -> [512,32,32,32], k3 s2 p1, relu ----
// window loaded once per (pixel, ic); all 32 oc accumulated in VGPRs
__global__ __launch_bounds__(256) void conv1_k(const float* __restrict__ frames,
                                               const float* __restrict__ W,
                                               const float* __restrict__ bias,
                                               float* __restrict__ out) {
  __shared__ __align__(16) float sIn[12288];
  int bt = blockIdx.x, tid = threadIdx.x;
  const float4* src = (const float4*)(frames + (size_t)bt * 12288);
  for (int i = tid; i < 3072; i += 256) ((float4*)sIn)[i] = src[i];
  __syncthreads();
  for (int p = tid; p < 1024; p += 256) {
    int ho = p >> 5, wo = p & 31, hi0 = ho*2-1, wi0 = wo*2-1;
    float acc[32];
    #pragma unroll
    for (int j = 0; j < 32; ++j) acc[j] = bias[j];
    #pragma unroll
    for (int ic = 0; ic < 3; ++ic) {
      float win[9];
      #pragma unroll
      for (int kh = 0; kh < 3; ++kh) {
        int hi = hi0 + kh;
        #pragma unroll
        for (int kw = 0; kw < 3; ++kw) {
          int wi = wi0 + kw;
          win[kh*3+kw] = (hi>=0 && hi<64 && wi>=0 && wi<64) ? sIn[ic*4096 + hi*64 + wi] : 0.f;
        }
      }
      #pragma unroll
      for (int j = 0; j < 32; ++j) {
        const float* wp = W + (size_t)j*27 + ic*9;   // wave-uniform -> scalar loads
        #pragma unroll
        for (int k = 0; k < 9; ++k) acc[j] += win[k] * wp[k];
      }
    }
    #pragma unroll
    for (int j = 0; j < 32; ++j)
      out[(size_t)(bt*32 + j)*1024 + p] = fmaxf(acc[j], 0.f);
  }
}

// ---- conv2: [512,32,32,32] -> [512,64,16,16] ----
// one pixel/thread, 64 oc accumulators; window read once per ic (8x fewer LDS reads)
__global__ __launch_bounds__(256) void conv2_k(const float* __restrict__ in,
                                               const float* __restrict__ W,
                                               const float* __restrict__ bias,
                                               float* __restrict__ out) {
  __shared__ __align__(16) float sIn[32768];
  int bt = blockIdx.x, tid = threadIdx.x;
  const float4* src = (const float4*)(in + (size_t)bt * 32768);
  for (int i = tid; i < 8192; i += 256) ((float4*)sIn)[i] = src[i];
  __syncthreads();
  int ho = tid >> 4, wo = tid & 15, hi0 = ho*2-1, wi0 = wo*2-1;
  float acc[64];
  #pragma unroll
  for (int j = 0; j < 64; ++j) acc[j] = bias[j];
  #pragma unroll 1
  for (int ic = 0; ic < 32; ++ic) {
    float win[9];
    #pragma unroll
    for (int kh = 0; kh < 3; ++kh) {
      int hi = hi0 + kh;
      #pragma unroll
      for (int kw = 0; kw < 3; ++kw) {
        int wi = wi0 + kw;
        win[kh*3+kw] = (hi>=0 && hi<32 && wi>=0 && wi<32) ? sIn[ic*1024 + hi*32 + wi] : 0.f;
      }
    }
    const float* wb = W + ic*9;
    #pragma unroll
    for (int j = 0; j < 64; ++j) {
      const float* wp = wb + (size_t)j*288;          // wave-uniform -> scalar loads
      #pragma unroll
      for (int k = 0; k < 9; ++k) acc[j] += win[k] * wp[k];
    }
  }
  #pragma unroll
  for (int j = 0; j < 64; ++j)
    out[(size_t)(bt*64 + j)*256 + tid] = fmaxf(acc[j], 0.f);
}

// ---- conv3: [512,64,16,16] -> [512,128,8,8] ----
// one pixel/thread, 32 oc per wave-group; window read once per ic
__global__ __launch_bounds__(256) void conv3_k(const float* __restrict__ in,
                                               const float* __restrict__ W,
                                               const float* __restrict__ bias,
                                               float* __restrict__ out) {
  __shared__ __align__(16) float sIn[16384];
  int bt = blockIdx.x, tid = threadIdx.x;
  const float4* src = (const float4*)(in + (size_t)bt * 16384);
  for (int i = tid; i < 4096; i += 256) ((float4*)sIn)[i] = src[i];
  __syncthreads();
  int pix = tid & 63, ocs = tid >> 6;   // ocs wave-uniform
  int ho = pix >> 3, wo = pix & 7, hi0 = ho*2-1, wi0 = wo*2-1;
  float acc[32];
  #pragma unroll
  for (int j = 0; j < 32; ++j) acc[j] = bias[ocs*32 + j];
  #pragma unroll 1
  for (int ic = 0; ic < 64; ++ic) {
    float win[9];
    #pragma unroll
    for (int kh = 0; kh < 3; ++kh) {
      int hi = hi0 + kh;
      #pragma unroll
      for (int kw = 0; kw < 3; ++kw) {
        int wi = wi0 + kw;
        win[kh*3+kw] = (hi>=0 && hi<16 && wi>=0 && wi<16) ? sIn[ic*256 + hi*16 + wi] : 0.f;
      }
    }
    const float* wb = W + (size_t)ocs*32*576 + ic*9;
    #pragma unroll
    for (int j = 0; j < 32; ++j) {
      const float* wp = wb + (size_t)j*576;          // wave-uniform -> scalar loads
      #pragma unroll
      for (int k = 0; k < 9; ++k) acc[j] += win[k] * wp[k];
    }
  }
  #pragma unroll
  for (int j = 0; j < 32; ++j)
    out[(size_t)(bt*128 + ocs*32 + j)*64 + pix] = fmaxf(acc[j], 0.f);
}

// ---- embed: node[bt,n,e] = sum_c c3[bt,c,n] * We[c,e] + be[e] ----
__global__ __launch_bounds__(256) void embed_k(const float* __restrict__ c3,
                                               const float* __restrict__ We,
                                               const float* __restrict__ be,
                                               float* __restrict__ node) {
  __shared__ float sF[64*133];
  __shared__ __align__(16) float sWe[8192];
  int bt = blockIdx.x, tid = threadIdx.x;
  const float* src = c3 + (size_t)bt * 8192;
  for (int i = tid; i < 8192; i += 256) sF[(i & 63)*133 + (i >> 6)] = src[i];
  const float4* w4 = (const float4*)We;
  for (int i = tid; i < 2048; i += 256) ((float4*)sWe)[i] = w4[i];
  __syncthreads();
  int lane = tid & 63, w = tid >> 6, nsub = lane >> 4, eb = lane & 15;
  int n0 = w*16 + nsub*4, e0 = eb*4;
  float acc[4][4];
  #pragma unroll
  for (int jj = 0; jj < 4; ++jj)
    #pragma unroll
    for (int ee = 0; ee < 4; ++ee) acc[jj][ee] = be[e0+ee];
  for (int c = 0; c < 128; ++c) {
    float a0 = sF[(n0+0)*133+c];
    float a1 = sF[(n0+1)*133+c];
    float a2 = sF[(n0+2)*133+c];
    float a3 = sF[(n0+3)*133+c];
    const float4 bv = *(const float4*)&sWe[c*64 + e0];
    acc[0][0]+=a0*bv.x; acc[0][1]+=a0*bv.y; acc[0][2]+=a0*bv.z; acc[0][3]+=a0*bv.w;
    acc[1][0]+=a1*bv.x; acc[1][1]+=a1*bv.y; acc[1][2]+=a1*bv.z; acc[1][3]+=a1*bv.w;
    acc[2][0]+=a2*bv.x; acc[2][1]+=a2*bv.y; acc[2][2]+=a2*bv.z; acc[2][3]+=a2*bv.w;
    acc[3][0]+=a3*bv.x; acc[3][1]+=a3*bv.y; acc[3][2]+=a3*bv.z; acc[3][3]+=a3*bv.w;
  }
  float4* nd = (float4*)(node + (size_t)bt * 4096);
  #pragma unroll
  for (int jj = 0; jj < 4; ++jj)
    nd[(n0+jj)*16 + eb] = make_float4(acc[jj][0], acc[jj][1], acc[jj][2], acc[jj][3]);
}

// ---- prep: A2=A@A ; gx = x@Wx0 + A@(x@Wx1) + A2@(x@Wx2); emit bf16 A, A2 + fp32 gx ----
__global__ __launch_bounds__(256) void prep_k(const float* __restrict__ adj,
                                              const float* __restrict__ node,
                                              const float* __restrict__ Wx,
                                              unsigned short* __restrict__ Abf,
                                              unsigned short* __restrict__ A2bf,
                                              float* __restrict__ gxg) {
  __shared__ __align__(16) float sA[64*SH], sA2[64*SH], sN[64*SH], sZ[64*SH];
  __shared__ __align__(16) float sWx[12288];
  int bt = blockIdx.x, tid = threadIdx.x;
  {
    const float4* a4 = (const float4*)(adj + (size_t)bt * 4096);
    const float4* n4 = (const float4*)(node + (size_t)bt * 4096);
    for (int i = tid; i < 1024; i += 256) {
      int r = i >> 4, c = (i & 15) * 4;
      *(float4*)&sA[r*SH+c] = a4[i];
      *(float4*)&sN[r*SH+c] = n4[i];
    }
    const float4* w4 = (const float4*)Wx;
    for (int i = tid; i < 3072; i += 256) ((float4*)sWx)[i] = w4[i];
  }
  __syncthreads();
  int lane = tid & 63, w = tid >> 6, nsub = lane >> 4, eb = lane & 15;
  int n0 = w*16 + nsub*4, e0 = eb*4;
  float4* gxout = (float4*)(gxg + (size_t)bt * 4096);
  for (int i = tid; i < 1024; i += 256) {
    int r = i >> 4, c0 = (i & 15) * 4;
    ushort4 o;
    o.x = bf16_rn(sA[r*SH+c0+0]); o.y = bf16_rn(sA[r*SH+c0+1]);
    o.z = bf16_rn(sA[r*SH+c0+2]); o.w = bf16_rn(sA[r*SH+c0+3]);
    *(ushort4*)&Abf[(size_t)bt*4096 + r*64 + c0] = o;
  }
  {
    float a2t[4][4] = {};
    mm16(sA, sA, SH, a2t, n0, e0);
    #pragma unroll
    for (int jj = 0; jj < 4; ++jj) {
      *(float4*)&sA2[(n0+jj)*SH+e0] = make_float4(a2t[jj][0], a2t[jj][1], a2t[jj][2], a2t[jj][3]);
      ushort4 o;
      o.x = bf16_rn(a2t[jj][0]); o.y = bf16_rn(a2t[jj][1]);
      o.z = bf16_rn(a2t[jj][2]); o.w = bf16_rn(a2t[jj][3]);
      *(ushort4*)&A2bf[(size_t)bt*4096 + (n0+jj)*64 + e0] = o;
    }
  }
  {
    float t[4][4] = {};
    mm16(sN, sWx + 4096, 64, t, n0, e0);       // z1 = x @ Wx1
    #pragma unroll
    for (int jj = 0; jj < 4; ++jj)
      *(float4*)&sZ[(n0+jj)*SH+e0] = make_float4(t[jj][0], t[jj][1], t[jj][2], t[jj][3]);
  }
  __syncthreads();
  float gx[4][4] = {};
  mm16(sA, sZ, SH, gx, n0, e0);                // gx = A @ z1
  __syncthreads();
  {
    float t[4][4] = {};
    mm16(sN, sWx + 8192, 64, t, n0, e0);       // z2 = x @ Wx2
    #pragma unroll
    for (int jj = 0; jj < 4; ++jj)
      *(float4*)&sZ[(n0+jj)*SH+e0] = make_float4(t[jj][0], t[jj][1], t[jj][2], t[jj][3]);
  }
  __syncthreads();
  mm16(sA2, sZ, SH, gx, n0, e0);               // gx += A2 @ z2
  mm16(sN, sWx, 64, gx, n0, e0);               // gx += x @ Wx0
  #pragma unroll
  for (int jj = 0; jj < 4; ++jj)
    gxout[(n0+jj)*16 + eb] = make_float4(gx[jj][0], gx[jj][1], gx[jj][2], gx[jj][3]);
}

// ---- Wh split: WhT_hi/lo[k3][dout][din] bf16 ----
__global__ void wsplit_k(const float* __restrict__ Wh,
                         unsigned short* __restrict__ WTh,
                         unsigned short* __restrict__ WTl) {
  int i = blockIdx.x * 256 + threadIdx.x;
  if (i < 3*4096) {
    int k3 = i >> 12, rem = i & 4095, din = rem >> 6, dout = rem & 63;
    float v = Wh[i];
    unsigned short hi = bf16_rn(v);
    WTh[k3*4096 + dout*64 + din] = hi;
    WTl[k3*4096 + dout*64 + din] = bf16_rn(v - bf16_tof(hi));
  }
}

#define MFMA(a, bb, cc) __builtin_amdgcn_mfma_f32_16x16x32_bf16((a), (bb), (cc), 0, 0, 0)

// ---- sequential recurrence via MFMA: one block per batch chain ----
__global__ __launch_bounds__(512, 2) void seq2_k(
    const unsigned short* __restrict__ Abf, const unsigned short* __restrict__ A2bf,
    const float* __restrict__ gxg, const float* __restrict__ h0,
    const unsigned short* __restrict__ WTh, const unsigned short* __restrict__ WTl,
    const float* __restrict__ bg, const float* __restrict__ tau, const float* __restrict__ Apv,
    float* __restrict__ mout, float* __restrict__ out) {
  __shared__ unsigned short sHh[64*72], sHl[64*72];
  __shared__ unsigned short sA[2][64*72], sA2[2][64*72];
  __shared__ unsigned szT[2][64*68];
  __shared__ float sPart[64*17];
  int b = blockIdx.x, tid = threadIdx.x;
  int lane = tid & 63, w = tid >> 6, g = lane >> 4, c = lane & 15;
  int mt = w & 3, nt0 = (w >> 2) * 2;
  int e0_ = nt0*16 + c, e1_ = e0_ + 16;
  int mrow = mt*16 + 4*g;
  float itau[2] = {1.f/tau[e0_], 1.f/tau[e1_]};
  float apv_[2] = {Apv[e0_], Apv[e1_]};
  float bgv_[2] = {bg[e0_], bg[e1_]};
  FU wf[3][2][2][2];
  #pragma unroll
  for (int k3 = 0; k3 < 3; ++k3)
    #pragma unroll
    for (int tt = 0; tt < 2; ++tt)
      #pragma unroll
      for (int kt = 0; kt < 2; ++kt) {
        int off = k3*4096 + ((nt0+tt)*16 + c)*64 + kt*32 + 8*g;
        wf[k3][tt][kt][0].q = *(const uint4*)(WTh + off);
        wf[k3][tt][kt][1].q = *(const uint4*)(WTl + off);
      }
  float hm[2][4];
  #pragma unroll
  for (int tt = 0; tt < 2; ++tt)
    #pragma unroll
    for (int r = 0; r < 4; ++r)
      hm[tt][r] = h0[(size_t)b*4096 + (mrow+r)*64 + (tt ? e1_ : e0_)];
  #pragma unroll
  for (int tt = 0; tt < 2; ++tt) {
    int e = tt ? e1_ : e0_;
    #pragma unroll
    for (int r = 0; r < 4; ++r) {
      unsigned short hi = bf16_rn(hm[tt][r]);
      sHh[(mrow+r)*72 + e] = hi;
      sHl[(mrow+r)*72 + e] = bf16_rn(hm[tt][r] - bf16_tof(hi));
    }
  }
  {
    uint4 pa  = *(const uint4*)(Abf  + (size_t)b*64*4096 + tid*8);
    uint4 pa2 = *(const uint4*)(A2bf + (size_t)b*64*4096 + tid*8);
    int row = tid >> 3, k0 = (tid & 7) * 8;
    *(uint4*)&sA[0][row*72 + k0]  = pa;
    *(uint4*)&sA2[0][row*72 + k0] = pa2;
  }
  __syncthreads();
  #pragma unroll 1
  for (int t = 0; t < 64; ++t) {
    int cur = t & 1;
    size_t bt = (size_t)b*64 + t;
    int tn = (t < 63) ? t + 1 : t;
    uint4 pa  = *(const uint4*)(Abf  + ((size_t)b*64 + tn)*4096 + tid*8);
    uint4 pa2 = *(const uint4*)(A2bf + ((size_t)b*64 + tn)*4096 + tid*8);
    float gxv[2][4];
    {
      const float* gp = gxg + bt*4096;
      #pragma unroll
      for (int tt = 0; tt < 2; ++tt)
        #pragma unroll
        for (int r = 0; r < 4; ++r)
          gxv[tt][r] = gp[(mrow+r)*64 + (tt ? e1_ : e0_)];
    }
    FU ha[2][2];
    #pragma unroll
    for (int kt = 0; kt < 2; ++kt) {
      int ao = (mt*16 + c)*72 + kt*32 + 8*g;
      ha[kt][0].q = *(const uint4*)&sHh[ao];
      ha[kt][1].q = *(const uint4*)&sHl[ao];
    }
    #pragma unroll
    for (int tt = 0; tt < 2; ++tt) {
      f32x4 a1 = {0.f, 0.f, 0.f, 0.f}, a2 = {0.f, 0.f, 0.f, 0.f};
      #pragma unroll
      for (int kt = 0; kt < 2; ++kt) {
        a1 = MFMA(ha[kt][0].v, wf[1][tt][kt][0].v, a1);
        a1 = MFMA(ha[kt][1].v, wf[1][tt][kt][0].v, a1);
        a1 = MFMA(ha[kt][0].v, wf[1][tt][kt][1].v, a1);
        a2 = MFMA(ha[kt][0].v, wf[2][tt][kt][0].v, a2);
        a2 = MFMA(ha[kt][1].v, wf[2][tt][kt][0].v, a2);
        a2 = MFMA(ha[kt][0].v, wf[2][tt][kt][1].v, a2);
      }
      int e = tt ? e1_ : e0_;
      unsigned pk1[4], pk2[4];
      #pragma unroll
      for (int r = 0; r < 4; ++r) {
        unsigned short h1 = bf16_rn(a1[r]);
        pk1[r] = (unsigned)h1 | ((unsigned)bf16_rn(a1[r] - bf16_tof(h1)) << 16);
        unsigned short h2 = bf16_rn(a2[r]);
        pk2[r] = (unsigned)h2 | ((unsigned)bf16_rn(a2[r] - bf16_tof(h2)) << 16);
      }
      *(uint4*)&szT[0][e*68 + mt*16 + 4*g] = make_uint4(pk1[0], pk1[1], pk1[2], pk1[3]);
      *(uint4*)&szT[1][e*68 + mt*16 + 4*g] = make_uint4(pk2[0], pk2[1], pk2[2], pk2[3]);
    }
    __syncthreads();   // B1
    f32x4 acc[2] = {{0.f,0.f,0.f,0.f}, {0.f,0.f,0.f,0.f}};
    #pragma unroll
    for (int kt = 0; kt < 2; ++kt) {
      FU aA, aA2;
      int ao = (mt*16 + c)*72 + kt*32 + 8*g;
      aA.q  = *(const uint4*)&sA[cur][ao];
      aA2.q = *(const uint4*)&sA2[cur][ao];
      #pragma unroll
      for (int tt = 0; tt < 2; ++tt) {
        int e = tt ? e1_ : e0_;
        acc[tt] = MFMA(ha[kt][0].v, wf[0][tt][kt][0].v, acc[tt]);
        acc[tt] = MFMA(ha[kt][1].v, wf[0][tt][kt][0].v, acc[tt]);
        acc[tt] = MFMA(ha[kt][0].v, wf[0][tt][kt][1].v, acc[tt]);
        uint4 q0 = *(const uint4*)&szT[0][e*68 + kt*32 + 8*g];
        uint4 q1 = *(const uint4*)&szT[0][e*68 + kt*32 + 8*g + 4];
        FU zh, zl; unpk(q0, q1, zh, zl);
        acc[tt] = MFMA(aA.v, zh.v, acc[tt]);
        acc[tt] = MFMA(aA.v, zl.v, acc[tt]);
        q0 = *(const uint4*)&szT[1][e*68 + kt*32 + 8*g];
        q1 = *(const uint4*)&szT[1][e*68 + kt*32 + 8*g + 4];
        unpk(q0, q1, zh, zl);
        acc[tt] = MFMA(aA2.v, zh.v, acc[tt]);
        acc[tt] = MFMA(aA2.v, zl.v, acc[tt]);
      }
    }
    #pragma unroll
    for (int tt = 0; tt < 2; ++tt) {
      int e = tt ? e1_ : e0_;
      float ps = 0.f;
      #pragma unroll
      for (int r = 0; r < 4; ++r) {
        float gc = acc[tt][r] + gxv[tt][r] + bgv_[tt];
        float f = tanh_f(gc);
        float h_ = hm[tt][r];
        float hn = h_ + DT_C * (-(itau[tt] + f) * h_ + f * apv_[tt]);
        hm[tt][r] = hn;
        ps += hn;
        unsigned short hi = bf16_rn(hn);
        sHh[(mrow+r)*72 + e] = hi;
        sHl[(mrow+r)*72 + e] = bf16_rn(hn - bf16_tof(hi));
      }
      sPart[e*17 + mt*4 + g] = ps;
    }
    {
      int row = tid >> 3, k0 = (tid & 7) * 8;
      *(uint4*)&sA[cur^1][row*72 + k0]  = pa;
      *(uint4*)&sA2[cur^1][row*72 + k0] = pa2;
    }
    __syncthreads();   // B3
    if (tid < 64) {
      float s = 0.f;
      #pragma unroll
      for (int j = 0; j < 16; ++j) s += sPart[tid*17 + j];
      mout[bt*64 + tid] = s * (1.0f / 64.0f);
    }
  }
  #pragma unroll
  for (int tt = 0; tt < 2; ++tt)
    #pragma unroll
    for (int r = 0; r < 4; ++r)
      out[512 + (size_t)b*4096 + (mrow+r)*64 + (tt ? e1_ : e0_)] = hm[tt][r];
}

// ---- decoder MLP for all (b,t) in parallel ----
__global__ __launch_bounds__(128) void dec_k(const float* __restrict__ mout,
                                             const float* __restrict__ Wd1, const float* __restrict__ bd1,
                                             const float* __restrict__ Wd2, const float* __restrict__ bd2,
                                             const float* __restrict__ Wd3, const float* __restrict__ bd3,
                                             float* __restrict__ out) {
  __shared__ float sm[64], sd1[128], sd2[64];
  int bt = blockIdx.x, tid = threadIdx.x;
  if (tid < 64) sm[tid] = mout[(size_t)bt*64 + tid];
  __syncthreads();
  {
    float a = bd1[tid];
    #pragma unroll 8
    for (int e = 0; e < 64; ++e) a += sm[e] * Wd1[e*128 + tid];
    sd1[tid] = fmaxf(a, 0.f);
  }
  __syncthreads();
  if (tid < 64) {
    float a = bd2[tid];
    #pragma unroll 8
    for (int i = 0; i < 128; ++i) a += sd1[i] * Wd2[i*64 + tid];
    sd2[tid] = fmaxf(a, 0.f);
  }
  __syncthreads();
  if (tid < 64) {
    float p = sd2[tid] * Wd3[tid];
    #pragma unroll
    for (int off = 32; off > 0; off >>= 1) p += __shfl_down(p, off, 64);
    if (tid == 0) out[bt] = p + bd3[0];
  }
}

extern "C" void kernel_launch(void* const* d_in, const int* in_sizes, int n_in,
                              void* d_out, int out_size, void* d_ws, size_t ws_size,
                              hipStream_t stream) {
  const float* frames = (const float*)d_in[0];
  const float* adj    = (const float*)d_in[1];
  const float* h0     = (const float*)d_in[2];
  const float* Wc1 = (const float*)d_in[3];  const float* bc1 = (const float*)d_in[4];
  const float* Wc2 = (const float*)d_in[5];  const float* bc2 = (const float*)d_in[6];
  const float* Wc3 = (const float*)d_in[7];  const float* bc3 = (const float*)d_in[8];
  const float* We  = (const float*)d_in[9];  const float* be  = (const float*)d_in[10];
  const float* Wh  = (const float*)d_in[11]; const float* Wx  = (const float*)d_in[12];
  const float* bg  = (const float*)d_in[13]; const float* tau = (const float*)d_in[14];
  const float* Ap  = (const float*)d_in[15];
  const float* Wd1 = (const float*)d_in[16]; const float* bd1 = (const float*)d_in[17];
  const float* Wd2 = (const float*)d_in[18]; const float* bd2 = (const float*)d_in[19];
  const float* Wd3 = (const float*)d_in[20]; const float* bd3 = (const float*)d_in[21];

  float* ws = (float*)d_ws;
  float* c1   = ws;                         // [0, 16.78M)   conv1 out
  float* c2   = ws + 16777216;              // [16.78M, 25.17M) conv2 out
  float* c3   = ws;                         // reuse (c1 dead) conv3 out
  float* node = ws + 4194304;               // 2,097,152
  float* mo   = ws + 6291456;               // 32,768 (mean per b,t)
  float* gx   = ws + 8388608;               // 2,097,152 fp32
  unsigned short* Abf  = (unsigned short*)(ws + 10485760);  // 512*4096 bf16
  unsigned short* A2bf = (unsigned short*)(ws + 11534336);  // 512*4096 bf16
  unsigned short* WTh  = (unsigned short*)(ws + 12582912);  // 3*4096 bf16
  unsigned short* WTl  = (unsigned short*)(ws + 12589056);  // 3*4096 bf16
  float* out  = (float*)d_out;

  conv1_k<<<512, 256, 0, stream>>>(frames, Wc1, bc1, c1);
  conv2_k<<<512, 256, 0, stream>>>(c1, Wc2, bc2, c2);
  conv3_k<<<512, 256, 0, stream>>>(c2, Wc3, bc3, c3);
  embed_k<<<512, 256, 0, stream>>>(c3, We, be, node);
  wsplit_k<<<48, 256, 0, stream>>>(Wh, WTh, WTl);
  prep_k <<<512, 256, 0, stream>>>(adj, node, Wx, Abf, A2bf, gx);
  seq2_k <<<8,   512, 0, stream>>>(Abf, A2bf, gx, h0, WTh, WTl, bg, tau, Ap, mo, out);
  dec_k  <<<512, 128, 0, stream>>>(mo, Wd1, bd1, Wd2, bd2, Wd3, bd3, out);
}

// Round 5
// 388.807 us; speedup vs baseline: 2.4240x; 2.4240x over previous
//
#include <hip/hip_runtime.h>

#define SH 68            // padded LDS row stride (floats) for fp32 prep kernels
#define DT_C 0.1f

typedef short bfrag __attribute__((ext_vector_type(8)));     // 8 bf16
typedef _Float16 hfrag __attribute__((ext_vector_type(8)));  // 8 fp16
typedef float f32x4 __attribute__((ext_vector_type(4)));

union FU { bfrag v; unsigned short s[8]; uint4 q; };
union HU { hfrag v; unsigned short s[8]; uint4 q; };

__device__ __forceinline__ unsigned short bf16_rn(float x) {
  union { float f; unsigned u; } v; v.f = x;
  unsigned r = v.u + 0x7fffu + ((v.u >> 16) & 1u);
  return (unsigned short)(r >> 16);
}
__device__ __forceinline__ float bf16_tof(unsigned short h) {
  union { unsigned u; float f; } v; v.u = ((unsigned)h) << 16; return v.f;
}
__device__ __forceinline__ float tanh_f(float x) {
  return 1.0f - 2.0f / (__expf(2.0f * x) + 1.0f);
}
__device__ __forceinline__ void unpk(uint4 q0, uint4 q1, FU& h, FU& l) {
  unsigned u[8] = {q0.x, q0.y, q0.z, q0.w, q1.x, q1.y, q1.z, q1.w};
  #pragma unroll
  for (int i = 0; i < 8; ++i) {
    h.s[i] = (unsigned short)(u[i] & 0xffffu);
    l.s[i] = (unsigned short)(u[i] >> 16);
  }
}
// fp16 hi/lo split of a float
__device__ __forceinline__ void h16split(float v, unsigned short& hu, unsigned short& lu) {
  union { _Float16 h; unsigned short u; } a, b;
  a.h = (_Float16)v;
  b.h = (_Float16)(v - (float)a.h);
  hu = a.u; lu = b.u;
}
__device__ __forceinline__ unsigned short h16hi(float v) {
  union { _Float16 h; unsigned short u; } a; a.h = (_Float16)v; return a.u;
}

// ---- fp32 4x4-block 64-K matmul helper (A stride SH; acc += A[n0..][*] * B[*][e0..]) ----
__device__ __forceinline__ void mm16(const float* __restrict__ A,
                                     const float* __restrict__ B, int sb,
                                     float acc[4][4], int n0, int e0) {
  #pragma unroll 2
  for (int k = 0; k < 64; ++k) {
    float a0 = A[(n0+0)*SH+k];
    float a1 = A[(n0+1)*SH+k];
    float a2 = A[(n0+2)*SH+k];
    float a3 = A[(n0+3)*SH+k];
    const float4 bv = *(const float4*)(B + k*sb + e0);
    acc[0][0]+=a0*bv.x; acc[0][1]+=a0*bv.y; acc[0][2]+=a0*bv.z; acc[0][3]+=a0*bv.w;
    acc[1][0]+=a1*bv.x; acc[1][1]+=a1*bv.y; acc[1][2]+=a1*bv.z; acc[1][3]+=a1*bv.w;
    acc[2][0]+=a2*bv.x; acc[2][1]+=a2*bv.y; acc[2][2]+=a2*bv.z; acc[2][3]+=a2*bv.w;
    acc[3][0]+=a3*bv.x; acc[3][1]+=a3*bv.y; acc[3][2]+=a3*bv.z; acc[3][3]+=a3*bv.w;
  }
}

// ---- weight prep: Wc2[oc][ic][3][3] -> W2[oc][pos][ic] fp16 hi/lo (K=288) ----
__global__ __launch_bounds__(256) void wprep2_k(const float* __restrict__ W,
                                                unsigned short* __restrict__ Wh,
                                                unsigned short* __restrict__ Wl) {
  int i = blockIdx.x * 256 + threadIdx.x;   // 18432
  if (i < 18432) {
    int oc = i / 288, rem = i % 288, pos = rem >> 5, ic = rem & 31;
    float v = W[oc*288 + ic*9 + pos];
    h16split(v, Wh[i], Wl[i]);
  }
}
// ---- Wc3[oc][ic][3][3] -> W3[oc][pos][ic] fp16 hi/lo (K=576) ----
__global__ __launch_bounds__(256) void wprep3_k(const float* __restrict__ W,
                                                unsigned short* __restrict__ Wh,
                                                unsigned short* __restrict__ Wl) {
  int i = blockIdx.x * 256 + threadIdx.x;   // 73728
  if (i < 73728) {
    int oc = i / 576, rem = i % 576, pos = rem >> 6, ic = rem & 63;
    float v = W[oc*576 + ic*9 + pos];
    h16split(v, Wh[i], Wl[i]);
  }
}

// ---- conv1: [512,3,64,64] -> fp16 hi/lo planes in conv2-staging layout ----
// layout: [ks=oc>>3][ho(32)][p=wo&1][wh=wo>>1 (16)][il=oc&7], 32768 halves per bt per plane
__global__ __launch_bounds__(256) void conv1_k(const float* __restrict__ frames,
                                               const float* __restrict__ W,
                                               const float* __restrict__ bias,
                                               unsigned short* __restrict__ c1h,
                                               unsigned short* __restrict__ c1l) {
  __shared__ __align__(16) float sIn[12288];
  int bt = blockIdx.x, tid = threadIdx.x;
  const float4* src = (const float4*)(frames + (size_t)bt * 12288);
  for (int i = tid; i < 3072; i += 256) ((float4*)sIn)[i] = src[i];
  __syncthreads();
  for (int p = tid; p < 1024; p += 256) {
    int ho = p >> 5, wo = p & 31, hi0 = ho*2-1, wi0 = wo*2-1;
    int obase = (((ho*2 + (wo&1))*16 + (wo>>1)))*8;   // within [32][2][16][8] sub-block
    for (int ocb = 0; ocb < 4; ++ocb) {
      float acc[8];
      #pragma unroll
      for (int j = 0; j < 8; ++j) acc[j] = bias[ocb*8+j];
      for (int ic = 0; ic < 3; ++ic) {
        float win[9];
        #pragma unroll
        for (int kh = 0; kh < 3; ++kh) {
          int hi = hi0 + kh;
          #pragma unroll
          for (int kw = 0; kw < 3; ++kw) {
            int wi = wi0 + kw;
            win[kh*3+kw] = (hi>=0 && hi<64 && wi>=0 && wi<64) ? sIn[ic*4096 + hi*64 + wi] : 0.f;
          }
        }
        #pragma unroll
        for (int j = 0; j < 8; ++j) {
          const float* wp = W + (size_t)(ocb*8+j)*27 + ic*9;
          #pragma unroll
          for (int k = 0; k < 9; ++k) acc[j] += win[k] * wp[k];
        }
      }
      ushort hh[8], ll[8];
      #pragma unroll
      for (int j = 0; j < 8; ++j) h16split(fmaxf(acc[j], 0.f), hh[j], ll[j]);
      size_t dst = (size_t)bt*32768 + ocb*8192 + obase;
      *(uint4*)&c1h[dst] = *(uint4*)hh;
      *(uint4*)&c1l[dst] = *(uint4*)ll;
    }
  }
}

#define MFMAH(a, bb, cc) __builtin_amdgcn_mfma_f32_16x16x32_f16((a), (bb), (cc), 0, 0, 0)

// ---- conv2 implicit-GEMM MFMA: M=256 pix, N=64 oc, K=288 (9 pos x 32 ic) ----
// input LDS [4][32][2][16][8] fp16 hi/lo; weights from global [oc][pos][ic] hi/lo
// output (hi-only fp16) -> conv3-staging layout [ks=oc>>3][ho(16)][p][wh(8)][il]
__global__ __launch_bounds__(256) void conv2m_k(const unsigned short* __restrict__ c1h,
                                                const unsigned short* __restrict__ c1l,
                                                const unsigned short* __restrict__ W2h,
                                                const unsigned short* __restrict__ W2l,
                                                const float* __restrict__ bias,
                                                unsigned short* __restrict__ c2h) {
  __shared__ __align__(16) unsigned short sH[32768], sL[32768];
  int bt = blockIdx.x, tid = threadIdx.x;
  {
    const uint4* gh = (const uint4*)(c1h + (size_t)bt*32768);
    const uint4* gl = (const uint4*)(c1l + (size_t)bt*32768);
    for (int i = tid; i < 4096; i += 256) { ((uint4*)sH)[i] = gh[i]; ((uint4*)sL)[i] = gl[i]; }
  }
  __syncthreads();
  int lane = tid & 63, w = tid >> 6, g = lane >> 4, c = lane & 15;
  f32x4 acc[4][4] = {};
  const uint4 z4 = make_uint4(0,0,0,0);
  #pragma unroll
  for (int pos = 0; pos < 9; ++pos) {
    const int kh = pos / 3, kw = pos % 3;
    HU Ah[4], Al[4];
    #pragma unroll
    for (int m = 0; m < 4; ++m) {
      int pix = w*64 + m*16 + c;
      int ho = pix >> 4, wo = pix & 15;
      int hi = 2*ho - 1 + kh, wi = 2*wo - 1 + kw;
      bool ok = (hi >= 0) & (wi >= 0);          // upper bounds never exceeded
      int hic = ok ? hi : 0, wic = ok ? wi : 0;
      int a = (((g*32 + hic)*2 + (wic & 1))*16 + (wic >> 1))*8;
      uint4 vh = *(const uint4*)&sH[a];
      uint4 vl = *(const uint4*)&sL[a];
      Ah[m].q = ok ? vh : z4;
      Al[m].q = ok ? vl : z4;
    }
    HU Bh[4], Bl[4];
    #pragma unroll
    for (int n = 0; n < 4; ++n) {
      int off = (n*16 + c)*288 + pos*32 + g*8;
      Bh[n].q = *(const uint4*)(W2h + off);
      Bl[n].q = *(const uint4*)(W2l + off);
    }
    #pragma unroll
    for (int m = 0; m < 4; ++m)
      #pragma unroll
      for (int n = 0; n < 4; ++n) {
        acc[m][n] = MFMAH(Ah[m].v, Bh[n].v, acc[m][n]);
        acc[m][n] = MFMAH(Al[m].v, Bh[n].v, acc[m][n]);
        acc[m][n] = MFMAH(Ah[m].v, Bl[n].v, acc[m][n]);
      }
  }
  // epilogue: bias+relu, fp16 hi into conv3 staging layout
  #pragma unroll
  for (int n = 0; n < 4; ++n) {
    int oc = n*16 + c;
    float bv = bias[oc];
    int ks3 = oc >> 3, il = oc & 7;
    #pragma unroll
    for (int m = 0; m < 4; ++m) {
      #pragma unroll
      for (int r = 0; r < 4; ++r) {
        int pix = w*64 + m*16 + 4*g + r;
        int ho = pix >> 4, wo = pix & 15;
        float v = fmaxf(acc[m][n][r] + bv, 0.f);
        size_t dst = (size_t)bt*16384 + ((((ks3*16 + ho)*2 + (wo&1))*8 + (wo>>1)))*8 + il;
        c2h[dst] = h16hi(v);
      }
    }
  }
}

// ---- conv3 implicit-GEMM MFMA: M=64 pix, N=128 oc, K=576 (9 pos x 64 ic) -> fp32 c3 ----
__global__ __launch_bounds__(256) void conv3m_k(const unsigned short* __restrict__ c2h,
                                                const unsigned short* __restrict__ W3h,
                                                const unsigned short* __restrict__ W3l,
                                                const float* __restrict__ bias,
                                                float* __restrict__ c3) {
  __shared__ __align__(16) unsigned short sH[16384];
  int bt = blockIdx.x, tid = threadIdx.x;
  {
    const uint4* gh = (const uint4*)(c2h + (size_t)bt*16384);
    for (int i = tid; i < 2048; i += 256) ((uint4*)sH)[i] = gh[i];
  }
  __syncthreads();
  int lane = tid & 63, w = tid >> 6, g = lane >> 4, c = lane & 15;
  f32x4 acc[8] = {};
  const uint4 z4 = make_uint4(0,0,0,0);
  int pix = w*16 + c;                  // wave w owns M-tile w
  int ho = pix >> 3, wo = pix & 7;
  #pragma unroll
  for (int pos = 0; pos < 9; ++pos) {
    const int kh = pos / 3, kw = pos % 3;
    int hi = 2*ho - 1 + kh, wi = 2*wo - 1 + kw;
    bool ok = (hi >= 0) & (wi >= 0);
    int hic = ok ? hi : 0, wic = ok ? wi : 0;
    #pragma unroll
    for (int ih = 0; ih < 2; ++ih) {
      int icg = ih*4 + g;
      int a = ((((icg*16 + hic)*2 + (wic & 1))*8 + (wic >> 1)))*8;
      HU Ah;
      uint4 vh = *(const uint4*)&sH[a];
      Ah.q = ok ? vh : z4;
      #pragma unroll
      for (int n = 0; n < 8; ++n) {
        int off = (n*16 + c)*576 + pos*64 + ih*32 + g*8;
        HU Bh, Bl;
        Bh.q = *(const uint4*)(W3h + off);
        Bl.q = *(const uint4*)(W3l + off);
        acc[n] = MFMAH(Ah.v, Bh.v, acc[n]);
        acc[n] = MFMAH(Ah.v, Bl.v, acc[n]);
      }
    }
  }
  #pragma unroll
  for (int n = 0; n < 8; ++n) {
    int oc = n*16 + c;
    float bv = bias[oc];
    #pragma unroll
    for (int r = 0; r < 4; ++r) {
      int po = w*16 + 4*g + r;
      c3[(size_t)(bt*128 + oc)*64 + po] = fmaxf(acc[n][r] + bv, 0.f);
    }
  }
}

// ---- embed: node[bt,n,e] = sum_c c3[bt,c,n] * We[c,e] + be[e] ----
__global__ __launch_bounds__(256) void embed_k(const float* __restrict__ c3,
                                               const float* __restrict__ We,
                                               const float* __restrict__ be,
                                               float* __restrict__ node) {
  __shared__ float sF[64*133];
  __shared__ __align__(16) float sWe[8192];
  int bt = blockIdx.x, tid = threadIdx.x;
  const float* src = c3 + (size_t)bt * 8192;
  for (int i = tid; i < 8192; i += 256) sF[(i & 63)*133 + (i >> 6)] = src[i];
  const float4* w4 = (const float4*)We;
  for (int i = tid; i < 2048; i += 256) ((float4*)sWe)[i] = w4[i];
  __syncthreads();
  int lane = tid & 63, w = tid >> 6, nsub = lane >> 4, eb = lane & 15;
  int n0 = w*16 + nsub*4, e0 = eb*4;
  float acc[4][4];
  #pragma unroll
  for (int jj = 0; jj < 4; ++jj)
    #pragma unroll
    for (int ee = 0; ee < 4; ++ee) acc[jj][ee] = be[e0+ee];
  for (int c = 0; c < 128; ++c) {
    float a0 = sF[(n0+0)*133+c];
    float a1 = sF[(n0+1)*133+c];
    float a2 = sF[(n0+2)*133+c];
    float a3 = sF[(n0+3)*133+c];
    const float4 bv = *(const float4*)&sWe[c*64 + e0];
    acc[0][0]+=a0*bv.x; acc[0][1]+=a0*bv.y; acc[0][2]+=a0*bv.z; acc[0][3]+=a0*bv.w;
    acc[1][0]+=a1*bv.x; acc[1][1]+=a1*bv.y; acc[1][2]+=a1*bv.z; acc[1][3]+=a1*bv.w;
    acc[2][0]+=a2*bv.x; acc[2][1]+=a2*bv.y; acc[2][2]+=a2*bv.z; acc[2][3]+=a2*bv.w;
    acc[3][0]+=a3*bv.x; acc[3][1]+=a3*bv.y; acc[3][2]+=a3*bv.z; acc[3][3]+=a3*bv.w;
  }
  float4* nd = (float4*)(node + (size_t)bt * 4096);
  #pragma unroll
  for (int jj = 0; jj < 4; ++jj)
    nd[(n0+jj)*16 + eb] = make_float4(acc[jj][0], acc[jj][1], acc[jj][2], acc[jj][3]);
}

// ---- prep: A2=A@A ; gx = x@Wx0 + A@(x@Wx1) + A2@(x@Wx2); emit bf16 A, A2 + fp32 gx ----
__global__ __launch_bounds__(256) void prep_k(const float* __restrict__ adj,
                                              const float* __restrict__ node,
                                              const float* __restrict__ Wx,
                                              unsigned short* __restrict__ Abf,
                                              unsigned short* __restrict__ A2bf,
                                              float* __restrict__ gxg) {
  __shared__ __align__(16) float sA[64*SH], sA2[64*SH], sN[64*SH], sZ[64*SH];
  __shared__ __align__(16) float sWx[12288];
  int bt = blockIdx.x, tid = threadIdx.x;
  {
    const float4* a4 = (const float4*)(adj + (size_t)bt * 4096);
    const float4* n4 = (const float4*)(node + (size_t)bt * 4096);
    for (int i = tid; i < 1024; i += 256) {
      int r = i >> 4, c = (i & 15) * 4;
      *(float4*)&sA[r*SH+c] = a4[i];
      *(float4*)&sN[r*SH+c] = n4[i];
    }
    const float4* w4 = (const float4*)Wx;
    for (int i = tid; i < 3072; i += 256) ((float4*)sWx)[i] = w4[i];
  }
  __syncthreads();
  int lane = tid & 63, w = tid >> 6, nsub = lane >> 4, eb = lane & 15;
  int n0 = w*16 + nsub*4, e0 = eb*4;
  float4* gxout = (float4*)(gxg + (size_t)bt * 4096);
  for (int i = tid; i < 1024; i += 256) {
    int r = i >> 4, c0 = (i & 15) * 4;
    ushort4 o;
    o.x = bf16_rn(sA[r*SH+c0+0]); o.y = bf16_rn(sA[r*SH+c0+1]);
    o.z = bf16_rn(sA[r*SH+c0+2]); o.w = bf16_rn(sA[r*SH+c0+3]);
    *(ushort4*)&Abf[(size_t)bt*4096 + r*64 + c0] = o;
  }
  {
    float a2t[4][4] = {};
    mm16(sA, sA, SH, a2t, n0, e0);
    #pragma unroll
    for (int jj = 0; jj < 4; ++jj) {
      *(float4*)&sA2[(n0+jj)*SH+e0] = make_float4(a2t[jj][0], a2t[jj][1], a2t[jj][2], a2t[jj][3]);
      ushort4 o;
      o.x = bf16_rn(a2t[jj][0]); o.y = bf16_rn(a2t[jj][1]);
      o.z = bf16_rn(a2t[jj][2]); o.w = bf16_rn(a2t[jj][3]);
      *(ushort4*)&A2bf[(size_t)bt*4096 + (n0+jj)*64 + e0] = o;
    }
  }
  {
    float t[4][4] = {};
    mm16(sN, sWx + 4096, 64, t, n0, e0);       // z1 = x @ Wx1
    #pragma unroll
    for (int jj = 0; jj < 4; ++jj)
      *(float4*)&sZ[(n0+jj)*SH+e0] = make_float4(t[jj][0], t[jj][1], t[jj][2], t[jj][3]);
  }
  __syncthreads();
  float gx[4][4] = {};
  mm16(sA, sZ, SH, gx, n0, e0);                // gx = A @ z1
  __syncthreads();
  {
    float t[4][4] = {};
    mm16(sN, sWx + 8192, 64, t, n0, e0);       // z2 = x @ Wx2
    #pragma unroll
    for (int jj = 0; jj < 4; ++jj)
      *(float4*)&sZ[(n0+jj)*SH+e0] = make_float4(t[jj][0], t[jj][1], t[jj][2], t[jj][3]);
  }
  __syncthreads();
  mm16(sA2, sZ, SH, gx, n0, e0);               // gx += A2 @ z2
  mm16(sN, sWx, 64, gx, n0, e0);               // gx += x @ Wx0
  #pragma unroll
  for (int jj = 0; jj < 4; ++jj)
    gxout[(n0+jj)*16 + eb] = make_float4(gx[jj][0], gx[jj][1], gx[jj][2], gx[jj][3]);
}

// ---- Wh split: WhT_hi/lo[k3][dout][din] bf16 ----
__global__ void wsplit_k(const float* __restrict__ Wh,
                         unsigned short* __restrict__ WTh,
                         unsigned short* __restrict__ WTl) {
  int i = blockIdx.x * 256 + threadIdx.x;
  if (i < 3*4096) {
    int k3 = i >> 12, rem = i & 4095, din = rem >> 6, dout = rem & 63;
    float v = Wh[i];
    unsigned short hi = bf16_rn(v);
    WTh[k3*4096 + dout*64 + din] = hi;
    WTl[k3*4096 + dout*64 + din] = bf16_rn(v - bf16_tof(hi));
  }
}

#define MFMA(a, bb, cc) __builtin_amdgcn_mfma_f32_16x16x32_bf16((a), (bb), (cc), 0, 0, 0)

// ---- sequential recurrence via MFMA: one block per batch chain ----
__global__ __launch_bounds__(512, 2) void seq2_k(
    const unsigned short* __restrict__ Abf, const unsigned short* __restrict__ A2bf,
    const float* __restrict__ gxg, const float* __restrict__ h0,
    const unsigned short* __restrict__ WTh, const unsigned short* __restrict__ WTl,
    const float* __restrict__ bg, const float* __restrict__ tau, const float* __restrict__ Apv,
    float* __restrict__ mout, float* __restrict__ out) {
  __shared__ unsigned short sHh[64*72], sHl[64*72];
  __shared__ unsigned short sA[2][64*72], sA2[2][64*72];
  __shared__ unsigned szT[2][64*68];
  __shared__ float sPart[64*17];
  int b = blockIdx.x, tid = threadIdx.x;
  int lane = tid & 63, w = tid >> 6, g = lane >> 4, c = lane & 15;
  int mt = w & 3, nt0 = (w >> 2) * 2;
  int e0_ = nt0*16 + c, e1_ = e0_ + 16;
  int mrow = mt*16 + 4*g;
  float itau[2] = {1.f/tau[e0_], 1.f/tau[e1_]};
  float apv_[2] = {Apv[e0_], Apv[e1_]};
  float bgv_[2] = {bg[e0_], bg[e1_]};
  FU wf[3][2][2][2];
  #pragma unroll
  for (int k3 = 0; k3 < 3; ++k3)
    #pragma unroll
    for (int tt = 0; tt < 2; ++tt)
      #pragma unroll
      for (int kt = 0; kt < 2; ++kt) {
        int off = k3*4096 + ((nt0+tt)*16 + c)*64 + kt*32 + 8*g;
        wf[k3][tt][kt][0].q = *(const uint4*)(WTh + off);
        wf[k3][tt][kt][1].q = *(const uint4*)(WTl + off);
      }
  float hm[2][4];
  #pragma unroll
  for (int tt = 0; tt < 2; ++tt)
    #pragma unroll
    for (int r = 0; r < 4; ++r)
      hm[tt][r] = h0[(size_t)b*4096 + (mrow+r)*64 + (tt ? e1_ : e0_)];
  #pragma unroll
  for (int tt = 0; tt < 2; ++tt) {
    int e = tt ? e1_ : e0_;
    #pragma unroll
    for (int r = 0; r < 4; ++r) {
      unsigned short hi = bf16_rn(hm[tt][r]);
      sHh[(mrow+r)*72 + e] = hi;
      sHl[(mrow+r)*72 + e] = bf16_rn(hm[tt][r] - bf16_tof(hi));
    }
  }
  {
    uint4 pa  = *(const uint4*)(Abf  + (size_t)b*64*4096 + tid*8);
    uint4 pa2 = *(const uint4*)(A2bf + (size_t)b*64*4096 + tid*8);
    int row = tid >> 3, k0 = (tid & 7) * 8;
    *(uint4*)&sA[0][row*72 + k0]  = pa;
    *(uint4*)&sA2[0][row*72 + k0] = pa2;
  }
  __syncthreads();
  #pragma unroll 1
  for (int t = 0; t < 64; ++t) {
    int cur = t & 1;
    size_t bt = (size_t)b*64 + t;
    int tn = (t < 63) ? t + 1 : t;
    uint4 pa  = *(const uint4*)(Abf  + ((size_t)b*64 + tn)*4096 + tid*8);
    uint4 pa2 = *(const uint4*)(A2bf + ((size_t)b*64 + tn)*4096 + tid*8);
    float gxv[2][4];
    {
      const float* gp = gxg + bt*4096;
      #pragma unroll
      for (int tt = 0; tt < 2; ++tt)
        #pragma unroll
        for (int r = 0; r < 4; ++r)
          gxv[tt][r] = gp[(mrow+r)*64 + (tt ? e1_ : e0_)];
    }
    FU ha[2][2];
    #pragma unroll
    for (int kt = 0; kt < 2; ++kt) {
      int ao = (mt*16 + c)*72 + kt*32 + 8*g;
      ha[kt][0].q = *(const uint4*)&sHh[ao];
      ha[kt][1].q = *(const uint4*)&sHl[ao];
    }
    #pragma unroll
    for (int tt = 0; tt < 2; ++tt) {
      f32x4 a1 = {0.f, 0.f, 0.f, 0.f}, a2 = {0.f, 0.f, 0.f, 0.f};
      #pragma unroll
      for (int kt = 0; kt < 2; ++kt) {
        a1 = MFMA(ha[kt][0].v, wf[1][tt][kt][0].v, a1);
        a1 = MFMA(ha[kt][1].v, wf[1][tt][kt][0].v, a1);
        a1 = MFMA(ha[kt][0].v, wf[1][tt][kt][1].v, a1);
        a2 = MFMA(ha[kt][0].v, wf[2][tt][kt][0].v, a2);
        a2 = MFMA(ha[kt][1].v, wf[2][tt][kt][0].v, a2);
        a2 = MFMA(ha[kt][0].v, wf[2][tt][kt][1].v, a2);
      }
      int e = tt ? e1_ : e0_;
      unsigned pk1[4], pk2[4];
      #pragma unroll
      for (int r = 0; r < 4; ++r) {
        unsigned short h1 = bf16_rn(a1[r]);
        pk1[r] = (unsigned)h1 | ((unsigned)bf16_rn(a1[r] - bf16_tof(h1)) << 16);
        unsigned short h2 = bf16_rn(a2[r]);
        pk2[r] = (unsigned)h2 | ((unsigned)bf16_rn(a2[r] - bf16_tof(h2)) << 16);
      }
      *(uint4*)&szT[0][e*68 + mt*16 + 4*g] = make_uint4(pk1[0], pk1[1], pk1[2], pk1[3]);
      *(uint4*)&szT[1][e*68 + mt*16 + 4*g] = make_uint4(pk2[0], pk2[1], pk2[2], pk2[3]);
    }
    __syncthreads();   // B1
    f32x4 acc[2] = {{0.f,0.f,0.f,0.f}, {0.f,0.f,0.f,0.f}};
    #pragma unroll
    for (int kt = 0; kt < 2; ++kt) {
      FU aA, aA2;
      int ao = (mt*16 + c)*72 + kt*32 + 8*g;
      aA.q  = *(const uint4*)&sA[cur][ao];
      aA2.q = *(const uint4*)&sA2[cur][ao];
      #pragma unroll
      for (int tt = 0; tt < 2; ++tt) {
        int e = tt ? e1_ : e0_;
        acc[tt] = MFMA(ha[kt][0].v, wf[0][tt][kt][0].v, acc[tt]);
        acc[tt] = MFMA(ha[kt][1].v, wf[0][tt][kt][0].v, acc[tt]);
        acc[tt] = MFMA(ha[kt][0].v, wf[0][tt][kt][1].v, acc[tt]);
        uint4 q0 = *(const uint4*)&szT[0][e*68 + kt*32 + 8*g];
        uint4 q1 = *(const uint4*)&szT[0][e*68 + kt*32 + 8*g + 4];
        FU zh, zl; unpk(q0, q1, zh, zl);
        acc[tt] = MFMA(aA.v, zh.v, acc[tt]);
        acc[tt] = MFMA(aA.v, zl.v, acc[tt]);
        q0 = *(const uint4*)&szT[1][e*68 + kt*32 + 8*g];
        q1 = *(const uint4*)&szT[1][e*68 + kt*32 + 8*g + 4];
        unpk(q0, q1, zh, zl);
        acc[tt] = MFMA(aA2.v, zh.v, acc[tt]);
        acc[tt] = MFMA(aA2.v, zl.v, acc[tt]);
      }
    }
    #pragma unroll
    for (int tt = 0; tt < 2; ++tt) {
      int e = tt ? e1_ : e0_;
      float ps = 0.f;
      #pragma unroll
      for (int r = 0; r < 4; ++r) {
        float gc = acc[tt][r] + gxv[tt][r] + bgv_[tt];
        float f = tanh_f(gc);
        float h_ = hm[tt][r];
        float hn = h_ + DT_C * (-(itau[tt] + f) * h_ + f * apv_[tt]);
        hm[tt][r] = hn;
        ps += hn;
        unsigned short hi = bf16_rn(hn);
        sHh[(mrow+r)*72 + e] = hi;
        sHl[(mrow+r)*72 + e] = bf16_rn(hn - bf16_tof(hi));
      }
      sPart[e*17 + mt*4 + g] = ps;
    }
    {
      int row = tid >> 3, k0 = (tid & 7) * 8;
      *(uint4*)&sA[cur^1][row*72 + k0]  = pa;
      *(uint4*)&sA2[cur^1][row*72 + k0] = pa2;
    }
    __syncthreads();   // B3
    if (tid < 64) {
      float s = 0.f;
      #pragma unroll
      for (int j = 0; j < 16; ++j) s += sPart[tid*17 + j];
      mout[bt*64 + tid] = s * (1.0f / 64.0f);
    }
  }
  #pragma unroll
  for (int tt = 0; tt < 2; ++tt)
    #pragma unroll
    for (int r = 0; r < 4; ++r)
      out[512 + (size_t)b*4096 + (mrow+r)*64 + (tt ? e1_ : e0_)] = hm[tt][r];
}

// ---- decoder MLP for all (b,t) in parallel ----
__global__ __launch_bounds__(128) void dec_k(const float* __restrict__ mout,
                                             const float* __restrict__ Wd1, const float* __restrict__ bd1,
                                             const float* __restrict__ Wd2, const float* __restrict__ bd2,
                                             const float* __restrict__ Wd3, const float* __restrict__ bd3,
                                             float* __restrict__ out) {
  __shared__ float sm[64], sd1[128], sd2[64];
  int bt = blockIdx.x, tid = threadIdx.x;
  if (tid < 64) sm[tid] = mout[(size_t)bt*64 + tid];
  __syncthreads();
  {
    float a = bd1[tid];
    #pragma unroll 8
    for (int e = 0; e < 64; ++e) a += sm[e] * Wd1[e*128 + tid];
    sd1[tid] = fmaxf(a, 0.f);
  }
  __syncthreads();
  if (tid < 64) {
    float a = bd2[tid];
    #pragma unroll 8
    for (int i = 0; i < 128; ++i) a += sd1[i] * Wd2[i*64 + tid];
    sd2[tid] = fmaxf(a, 0.f);
  }
  __syncthreads();
  if (tid < 64) {
    float p = sd2[tid] * Wd3[tid];
    #pragma unroll
    for (int off = 32; off > 0; off >>= 1) p += __shfl_down(p, off, 64);
    if (tid == 0) out[bt] = p + bd3[0];
  }
}

extern "C" void kernel_launch(void* const* d_in, const int* in_sizes, int n_in,
                              void* d_out, int out_size, void* d_ws, size_t ws_size,
                              hipStream_t stream) {
  const float* frames = (const float*)d_in[0];
  const float* adj    = (const float*)d_in[1];
  const float* h0     = (const float*)d_in[2];
  const float* Wc1 = (const float*)d_in[3];  const float* bc1 = (const float*)d_in[4];
  const float* Wc2 = (const float*)d_in[5];  const float* bc2 = (const float*)d_in[6];
  const float* Wc3 = (const float*)d_in[7];  const float* bc3 = (const float*)d_in[8];
  const float* We  = (const float*)d_in[9];  const float* be  = (const float*)d_in[10];
  const float* Wh  = (const float*)d_in[11]; const float* Wx  = (const float*)d_in[12];
  const float* bg  = (const float*)d_in[13]; const float* tau = (const float*)d_in[14];
  const float* Ap  = (const float*)d_in[15];
  const float* Wd1 = (const float*)d_in[16]; const float* bd1 = (const float*)d_in[17];
  const float* Wd2 = (const float*)d_in[18]; const float* bd2 = (const float*)d_in[19];
  const float* Wd3 = (const float*)d_in[20]; const float* bd3 = (const float*)d_in[21];

  float* ws = (float*)d_ws;
  // Workspace map (float offsets; validated 25,165,824-float budget).
  // Phase 1 (conv chain):
  //   c1h  [0,          8,388,608)   16.78M halves (conv1 out hi)   -- dead after conv2m
  //   c1l  [8,388,608, 16,777,216)   16.78M halves (conv1 out lo)   -- dead after conv2m
  //   c2h  [16,777,216, 20,971,520)   8.39M halves (conv2 out hi)   -- dead after conv3m
  //   weights [20,971,520, ~21,076,000): W2h/W2l/W3h/W3l/WTh/WTl (persist)
  // Phase 2 (reuses dead c1 regions):
  //   c3   [0, 4,194,304)  node [4,194,304, 6,291,456)  gx [6,291,456, 8,388,608)
  //   Abf  [8,388,608, 9,437,184)  A2bf [9,437,184, 10,485,760)  mo [10,485,760, ..)
  unsigned short* c1h = (unsigned short*)(ws);
  unsigned short* c1l = (unsigned short*)(ws + 8388608);
  unsigned short* c2h = (unsigned short*)(ws + 16777216);
  unsigned short* W2h = (unsigned short*)(ws + 20971520);
  unsigned short* W2l = (unsigned short*)(ws + 20980736);
  unsigned short* W3h = (unsigned short*)(ws + 20989952);
  unsigned short* W3l = (unsigned short*)(ws + 21026816);
  unsigned short* WTh = (unsigned short*)(ws + 21063680);
  unsigned short* WTl = (unsigned short*)(ws + 21069824);
  float* c3   = ws;                              // reuse c1h (dead after conv2m)
  float* node = ws + 4194304;
  float* gx   = ws + 6291456;
  unsigned short* Abf  = (unsigned short*)(ws + 8388608);   // reuse c1l (dead)
  unsigned short* A2bf = (unsigned short*)(ws + 9437184);
  float* mo   = ws + 10485760;
  float* out  = (float*)d_out;

  wprep2_k<<<72,  256, 0, stream>>>(Wc2, W2h, W2l);
  wprep3_k<<<288, 256, 0, stream>>>(Wc3, W3h, W3l);
  wsplit_k<<<48,  256, 0, stream>>>(Wh, WTh, WTl);
  conv1_k <<<512, 256, 0, stream>>>(frames, Wc1, bc1, c1h, c1l);
  conv2m_k<<<512, 256, 0, stream>>>(c1h, c1l, W2h, W2l, bc2, c2h);
  conv3m_k<<<512, 256, 0, stream>>>(c2h, W3h, W3l, bc3, c3);
  embed_k <<<512, 256, 0, stream>>>(c3, We, be, node);
  prep_k  <<<512, 256, 0, stream>>>(adj, node, Wx, Abf, A2bf, gx);
  seq2_k  <<<8,   512, 0, stream>>>(Abf, A2bf, gx, h0, WTh, WTl, bg, tau, Ap, mo, out);
  dec_k   <<<512, 128, 0, stream>>>(mo, Wd1, bd1, Wd2, bd2, Wd3, bd3, out);
}

// Round 6
// 346.518 us; speedup vs baseline: 2.7198x; 1.1220x over previous
//
#include <hip/hip_runtime.h>

#define SH 68            // padded LDS row stride (floats) for fp32 prep kernels
#define DT_C 0.1f

typedef short bfrag __attribute__((ext_vector_type(8)));     // 8 bf16
typedef _Float16 hfrag __attribute__((ext_vector_type(8)));  // 8 fp16
typedef float f32x4 __attribute__((ext_vector_type(4)));

union FU { bfrag v; unsigned short s[8]; uint4 q; };
union HU { hfrag v; unsigned short s[8]; uint4 q; };

__device__ __forceinline__ unsigned short bf16_rn(float x) {
  union { float f; unsigned u; } v; v.f = x;
  unsigned r = v.u + 0x7fffu + ((v.u >> 16) & 1u);
  return (unsigned short)(r >> 16);
}
__device__ __forceinline__ float bf16_tof(unsigned short h) {
  union { unsigned u; float f; } v; v.u = ((unsigned)h) << 16; return v.f;
}
__device__ __forceinline__ float tanh_f(float x) {
  return 1.0f - 2.0f / (__expf(2.0f * x) + 1.0f);
}
// fp16 hi/lo split of a float
__device__ __forceinline__ void h16split(float v, unsigned short& hu, unsigned short& lu) {
  union { _Float16 h; unsigned short u; } a, b;
  a.h = (_Float16)v;
  b.h = (_Float16)(v - (float)a.h);
  hu = a.u; lu = b.u;
}
__device__ __forceinline__ unsigned short h16hi(float v) {
  union { _Float16 h; unsigned short u; } a; a.h = (_Float16)v; return a.u;
}

// ---- fp32 4x4-block 64-K matmul helper (A stride SH; acc += A[n0..][*] * B[*][e0..]) ----
__device__ __forceinline__ void mm16(const float* __restrict__ A,
                                     const float* __restrict__ B, int sb,
                                     float acc[4][4], int n0, int e0) {
  #pragma unroll 2
  for (int k = 0; k < 64; ++k) {
    float a0 = A[(n0+0)*SH+k];
    float a1 = A[(n0+1)*SH+k];
    float a2 = A[(n0+2)*SH+k];
    float a3 = A[(n0+3)*SH+k];
    const float4 bv = *(const float4*)(B + k*sb + e0);
    acc[0][0]+=a0*bv.x; acc[0][1]+=a0*bv.y; acc[0][2]+=a0*bv.z; acc[0][3]+=a0*bv.w;
    acc[1][0]+=a1*bv.x; acc[1][1]+=a1*bv.y; acc[1][2]+=a1*bv.z; acc[1][3]+=a1*bv.w;
    acc[2][0]+=a2*bv.x; acc[2][1]+=a2*bv.y; acc[2][2]+=a2*bv.z; acc[2][3]+=a2*bv.w;
    acc[3][0]+=a3*bv.x; acc[3][1]+=a3*bv.y; acc[3][2]+=a3*bv.z; acc[3][3]+=a3*bv.w;
  }
}

// ---- fused weight prep: Wc2 -> W2 fp16 hi/lo [oc][pos][ic] (18432),
//      Wc3 -> W3 fp16 hi/lo [oc][pos][ic] (73728), Wh -> WT bf16 hi/lo [k3][dout][din] (12288)
__global__ __launch_bounds__(256) void wprep_k(const float* __restrict__ Wc2,
                                               const float* __restrict__ Wc3,
                                               const float* __restrict__ Wh,
                                               unsigned short* __restrict__ W2h,
                                               unsigned short* __restrict__ W2l,
                                               unsigned short* __restrict__ W3h,
                                               unsigned short* __restrict__ W3l,
                                               unsigned short* __restrict__ WTh,
                                               unsigned short* __restrict__ WTl) {
  int i = blockIdx.x * 256 + threadIdx.x;
  if (i < 18432) {
    int oc = i / 288, rem = i % 288, pos = rem >> 5, ic = rem & 31;
    float v = Wc2[oc*288 + ic*9 + pos];
    h16split(v, W2h[i], W2l[i]);
  } else if (i < 18432 + 73728) {
    int j = i - 18432;
    int oc = j / 576, rem = j % 576, pos = rem >> 6, ic = rem & 63;
    float v = Wc3[oc*576 + ic*9 + pos];
    h16split(v, W3h[j], W3l[j]);
  } else if (i < 18432 + 73728 + 12288) {
    int j = i - 92160;
    int k3 = j >> 12, rem = j & 4095, din = rem >> 6, dout = rem & 63;
    float v = Wh[j];
    unsigned short hi = bf16_rn(v);
    WTh[k3*4096 + dout*64 + din] = hi;
    WTl[k3*4096 + dout*64 + din] = bf16_rn(v - bf16_tof(hi));
  }
}

// ---- conv1: [512,3,64,64] -> fp16 hi/lo planes in conv2-staging layout ----
// layout: [ks=oc>>3][ho(32)][p=wo&1][wh=wo>>1 (16)][il=oc&7], 32768 halves per bt per plane
__global__ __launch_bounds__(256) void conv1_k(const float* __restrict__ frames,
                                               const float* __restrict__ W,
                                               const float* __restrict__ bias,
                                               unsigned short* __restrict__ c1h,
                                               unsigned short* __restrict__ c1l) {
  __shared__ __align__(16) float sIn[12288];
  int bt = blockIdx.x, tid = threadIdx.x;
  const float4* src = (const float4*)(frames + (size_t)bt * 12288);
  for (int i = tid; i < 3072; i += 256) ((float4*)sIn)[i] = src[i];
  __syncthreads();
  for (int p = tid; p < 1024; p += 256) {
    int ho = p >> 5, wo = p & 31, hi0 = ho*2-1, wi0 = wo*2-1;
    int obase = (((ho*2 + (wo&1))*16 + (wo>>1)))*8;   // within [32][2][16][8] sub-block
    for (int ocb = 0; ocb < 4; ++ocb) {
      float acc[8];
      #pragma unroll
      for (int j = 0; j < 8; ++j) acc[j] = bias[ocb*8+j];
      for (int ic = 0; ic < 3; ++ic) {
        float win[9];
        #pragma unroll
        for (int kh = 0; kh < 3; ++kh) {
          int hi = hi0 + kh;
          #pragma unroll
          for (int kw = 0; kw < 3; ++kw) {
            int wi = wi0 + kw;
            win[kh*3+kw] = (hi>=0 && hi<64 && wi>=0 && wi<64) ? sIn[ic*4096 + hi*64 + wi] : 0.f;
          }
        }
        #pragma unroll
        for (int j = 0; j < 8; ++j) {
          const float* wp = W + (size_t)(ocb*8+j)*27 + ic*9;
          #pragma unroll
          for (int k = 0; k < 9; ++k) acc[j] += win[k] * wp[k];
        }
      }
      ushort hh[8], ll[8];
      #pragma unroll
      for (int j = 0; j < 8; ++j) h16split(fmaxf(acc[j], 0.f), hh[j], ll[j]);
      size_t dst = (size_t)bt*32768 + ocb*8192 + obase;
      *(uint4*)&c1h[dst] = *(uint4*)hh;
      *(uint4*)&c1l[dst] = *(uint4*)ll;
    }
  }
}

#define MFMAH(a, bb, cc) __builtin_amdgcn_mfma_f32_16x16x32_f16((a), (bb), (cc), 0, 0, 0)

// ---- conv2 implicit-GEMM MFMA: M=256 pix, N=64 oc, K=288 (9 pos x 32 ic) ----
__global__ __launch_bounds__(256) void conv2m_k(const unsigned short* __restrict__ c1h,
                                                const unsigned short* __restrict__ c1l,
                                                const unsigned short* __restrict__ W2h,
                                                const unsigned short* __restrict__ W2l,
                                                const float* __restrict__ bias,
                                                unsigned short* __restrict__ c2h) {
  __shared__ __align__(16) unsigned short sH[32768], sL[32768];
  int bt = blockIdx.x, tid = threadIdx.x;
  {
    const uint4* gh = (const uint4*)(c1h + (size_t)bt*32768);
    const uint4* gl = (const uint4*)(c1l + (size_t)bt*32768);
    for (int i = tid; i < 4096; i += 256) { ((uint4*)sH)[i] = gh[i]; ((uint4*)sL)[i] = gl[i]; }
  }
  __syncthreads();
  int lane = tid & 63, w = tid >> 6, g = lane >> 4, c = lane & 15;
  f32x4 acc[4][4] = {};
  const uint4 z4 = make_uint4(0,0,0,0);
  #pragma unroll
  for (int pos = 0; pos < 9; ++pos) {
    const int kh = pos / 3, kw = pos % 3;
    HU Ah[4], Al[4];
    #pragma unroll
    for (int m = 0; m < 4; ++m) {
      int pix = w*64 + m*16 + c;
      int ho = pix >> 4, wo = pix & 15;
      int hi = 2*ho - 1 + kh, wi = 2*wo - 1 + kw;
      bool ok = (hi >= 0) & (wi >= 0);
      int hic = ok ? hi : 0, wic = ok ? wi : 0;
      int a = (((g*32 + hic)*2 + (wic & 1))*16 + (wic >> 1))*8;
      uint4 vh = *(const uint4*)&sH[a];
      uint4 vl = *(const uint4*)&sL[a];
      Ah[m].q = ok ? vh : z4;
      Al[m].q = ok ? vl : z4;
    }
    HU Bh[4], Bl[4];
    #pragma unroll
    for (int n = 0; n < 4; ++n) {
      int off = (n*16 + c)*288 + pos*32 + g*8;
      Bh[n].q = *(const uint4*)(W2h + off);
      Bl[n].q = *(const uint4*)(W2l + off);
    }
    #pragma unroll
    for (int m = 0; m < 4; ++m)
      #pragma unroll
      for (int n = 0; n < 4; ++n) {
        acc[m][n] = MFMAH(Ah[m].v, Bh[n].v, acc[m][n]);
        acc[m][n] = MFMAH(Al[m].v, Bh[n].v, acc[m][n]);
        acc[m][n] = MFMAH(Ah[m].v, Bl[n].v, acc[m][n]);
      }
  }
  #pragma unroll
  for (int n = 0; n < 4; ++n) {
    int oc = n*16 + c;
    float bv = bias[oc];
    int ks3 = oc >> 3, il = oc & 7;
    #pragma unroll
    for (int m = 0; m < 4; ++m) {
      #pragma unroll
      for (int r = 0; r < 4; ++r) {
        int pix = w*64 + m*16 + 4*g + r;
        int ho = pix >> 4, wo = pix & 15;
        float v = fmaxf(acc[m][n][r] + bv, 0.f);
        size_t dst = (size_t)bt*16384 + ((((ks3*16 + ho)*2 + (wo&1))*8 + (wo>>1)))*8 + il;
        c2h[dst] = h16hi(v);
      }
    }
  }
}

// ---- conv3 implicit-GEMM MFMA: M=64 pix, N=128 oc, K=576 -> fp32 c3 ----
__global__ __launch_bounds__(256) void conv3m_k(const unsigned short* __restrict__ c2h,
                                                const unsigned short* __restrict__ W3h,
                                                const unsigned short* __restrict__ W3l,
                                                const float* __restrict__ bias,
                                                float* __restrict__ c3) {
  __shared__ __align__(16) unsigned short sH[16384];
  int bt = blockIdx.x, tid = threadIdx.x;
  {
    const uint4* gh = (const uint4*)(c2h + (size_t)bt*16384);
    for (int i = tid; i < 2048; i += 256) ((uint4*)sH)[i] = gh[i];
  }
  __syncthreads();
  int lane = tid & 63, w = tid >> 6, g = lane >> 4, c = lane & 15;
  f32x4 acc[8] = {};
  const uint4 z4 = make_uint4(0,0,0,0);
  int pix = w*16 + c;
  int ho = pix >> 3, wo = pix & 7;
  #pragma unroll
  for (int pos = 0; pos < 9; ++pos) {
    const int kh = pos / 3, kw = pos % 3;
    int hi = 2*ho - 1 + kh, wi = 2*wo - 1 + kw;
    bool ok = (hi >= 0) & (wi >= 0);
    int hic = ok ? hi : 0, wic = ok ? wi : 0;
    #pragma unroll
    for (int ih = 0; ih < 2; ++ih) {
      int icg = ih*4 + g;
      int a = ((((icg*16 + hic)*2 + (wic & 1))*8 + (wic >> 1)))*8;
      HU Ah;
      uint4 vh = *(const uint4*)&sH[a];
      Ah.q = ok ? vh : z4;
      #pragma unroll
      for (int n = 0; n < 8; ++n) {
        int off = (n*16 + c)*576 + pos*64 + ih*32 + g*8;
        HU Bh, Bl;
        Bh.q = *(const uint4*)(W3h + off);
        Bl.q = *(const uint4*)(W3l + off);
        acc[n] = MFMAH(Ah.v, Bh.v, acc[n]);
        acc[n] = MFMAH(Ah.v, Bl.v, acc[n]);
      }
    }
  }
  #pragma unroll
  for (int n = 0; n < 8; ++n) {
    int oc = n*16 + c;
    float bv = bias[oc];
    #pragma unroll
    for (int r = 0; r < 4; ++r) {
      int po = w*16 + 4*g + r;
      c3[(size_t)(bt*128 + oc)*64 + po] = fmaxf(acc[n][r] + bv, 0.f);
    }
  }
}

// ---- embed: node[bt,n,e] = sum_c c3[bt,c,n] * We[c,e] + be[e] ----
__global__ __launch_bounds__(256) void embed_k(const float* __restrict__ c3,
                                               const float* __restrict__ We,
                                               const float* __restrict__ be,
                                               float* __restrict__ node) {
  __shared__ float sF[64*133];
  __shared__ __align__(16) float sWe[8192];
  int bt = blockIdx.x, tid = threadIdx.x;
  const float* src = c3 + (size_t)bt * 8192;
  for (int i = tid; i < 8192; i += 256) sF[(i & 63)*133 + (i >> 6)] = src[i];
  const float4* w4 = (const float4*)We;
  for (int i = tid; i < 2048; i += 256) ((float4*)sWe)[i] = w4[i];
  __syncthreads();
  int lane = tid & 63, w = tid >> 6, nsub = lane >> 4, eb = lane & 15;
  int n0 = w*16 + nsub*4, e0 = eb*4;
  float acc[4][4];
  #pragma unroll
  for (int jj = 0; jj < 4; ++jj)
    #pragma unroll
    for (int ee = 0; ee < 4; ++ee) acc[jj][ee] = be[e0+ee];
  for (int c = 0; c < 128; ++c) {
    float a0 = sF[(n0+0)*133+c];
    float a1 = sF[(n0+1)*133+c];
    float a2 = sF[(n0+2)*133+c];
    float a3 = sF[(n0+3)*133+c];
    const float4 bv = *(const float4*)&sWe[c*64 + e0];
    acc[0][0]+=a0*bv.x; acc[0][1]+=a0*bv.y; acc[0][2]+=a0*bv.z; acc[0][3]+=a0*bv.w;
    acc[1][0]+=a1*bv.x; acc[1][1]+=a1*bv.y; acc[1][2]+=a1*bv.z; acc[1][3]+=a1*bv.w;
    acc[2][0]+=a2*bv.x; acc[2][1]+=a2*bv.y; acc[2][2]+=a2*bv.z; acc[2][3]+=a2*bv.w;
    acc[3][0]+=a3*bv.x; acc[3][1]+=a3*bv.y; acc[3][2]+=a3*bv.z; acc[3][3]+=a3*bv.w;
  }
  float4* nd = (float4*)(node + (size_t)bt * 4096);
  #pragma unroll
  for (int jj = 0; jj < 4; ++jj)
    nd[(n0+jj)*16 + eb] = make_float4(acc[jj][0], acc[jj][1], acc[jj][2], acc[jj][3]);
}

// ---- prep: A2=A@A ; gx = x@Wx0 + A@(x@Wx1) + A2@(x@Wx2); emit bf16 A, A2 + fp32 gx ----
__global__ __launch_bounds__(256) void prep_k(const float* __restrict__ adj,
                                              const float* __restrict__ node,
                                              const float* __restrict__ Wx,
                                              unsigned short* __restrict__ Abf,
                                              unsigned short* __restrict__ A2bf,
                                              float* __restrict__ gxg) {
  __shared__ __align__(16) float sA[64*SH], sA2[64*SH], sN[64*SH], sZ[64*SH];
  __shared__ __align__(16) float sWx[12288];
  int bt = blockIdx.x, tid = threadIdx.x;
  {
    const float4* a4 = (const float4*)(adj + (size_t)bt * 4096);
    const float4* n4 = (const float4*)(node + (size_t)bt * 4096);
    for (int i = tid; i < 1024; i += 256) {
      int r = i >> 4, c = (i & 15) * 4;
      *(float4*)&sA[r*SH+c] = a4[i];
      *(float4*)&sN[r*SH+c] = n4[i];
    }
    const float4* w4 = (const float4*)Wx;
    for (int i = tid; i < 3072; i += 256) ((float4*)sWx)[i] = w4[i];
  }
  __syncthreads();
  int lane = tid & 63, w = tid >> 6, nsub = lane >> 4, eb = lane & 15;
  int n0 = w*16 + nsub*4, e0 = eb*4;
  float4* gxout = (float4*)(gxg + (size_t)bt * 4096);
  for (int i = tid; i < 1024; i += 256) {
    int r = i >> 4, c0 = (i & 15) * 4;
    ushort4 o;
    o.x = bf16_rn(sA[r*SH+c0+0]); o.y = bf16_rn(sA[r*SH+c0+1]);
    o.z = bf16_rn(sA[r*SH+c0+2]); o.w = bf16_rn(sA[r*SH+c0+3]);
    *(ushort4*)&Abf[(size_t)bt*4096 + r*64 + c0] = o;
  }
  {
    float a2t[4][4] = {};
    mm16(sA, sA, SH, a2t, n0, e0);
    #pragma unroll
    for (int jj = 0; jj < 4; ++jj) {
      *(float4*)&sA2[(n0+jj)*SH+e0] = make_float4(a2t[jj][0], a2t[jj][1], a2t[jj][2], a2t[jj][3]);
      ushort4 o;
      o.x = bf16_rn(a2t[jj][0]); o.y = bf16_rn(a2t[jj][1]);
      o.z = bf16_rn(a2t[jj][2]); o.w = bf16_rn(a2t[jj][3]);
      *(ushort4*)&A2bf[(size_t)bt*4096 + (n0+jj)*64 + e0] = o;
    }
  }
  {
    float t[4][4] = {};
    mm16(sN, sWx + 4096, 64, t, n0, e0);       // z1 = x @ Wx1
    #pragma unroll
    for (int jj = 0; jj < 4; ++jj)
      *(float4*)&sZ[(n0+jj)*SH+e0] = make_float4(t[jj][0], t[jj][1], t[jj][2], t[jj][3]);
  }
  __syncthreads();
  float gx[4][4] = {};
  mm16(sA, sZ, SH, gx, n0, e0);                // gx = A @ z1
  __syncthreads();
  {
    float t[4][4] = {};
    mm16(sN, sWx + 8192, 64, t, n0, e0);       // z2 = x @ Wx2
    #pragma unroll
    for (int jj = 0; jj < 4; ++jj)
      *(float4*)&sZ[(n0+jj)*SH+e0] = make_float4(t[jj][0], t[jj][1], t[jj][2], t[jj][3]);
  }
  __syncthreads();
  mm16(sA2, sZ, SH, gx, n0, e0);               // gx += A2 @ z2
  mm16(sN, sWx, 64, gx, n0, e0);               // gx += x @ Wx0
  #pragma unroll
  for (int jj = 0; jj < 4; ++jj)
    gxout[(n0+jj)*16 + eb] = make_float4(gx[jj][0], gx[jj][1], gx[jj][2], gx[jj][3]);
}

#define MFMA(a, bb, cc) __builtin_amdgcn_mfma_f32_16x16x32_bf16((a), (bb), (cc), 0, 0, 0)

// ---- sequential recurrence via MFMA: one block per batch chain ----
// Precision scheme: Wh hi/lo bf16 (static -> correlated error killed);
// h, z, A, A2 operands single-bf16 (per-step uncorrelated rounding, ~2^-9).
// h master state stays fp32 in registers.
__global__ __launch_bounds__(512, 2) void seq2_k(
    const unsigned short* __restrict__ Abf, const unsigned short* __restrict__ A2bf,
    const float* __restrict__ gxg, const float* __restrict__ h0,
    const unsigned short* __restrict__ WTh, const unsigned short* __restrict__ WTl,
    const float* __restrict__ bg, const float* __restrict__ tau, const float* __restrict__ Apv,
    float* __restrict__ mout, float* __restrict__ out) {
  __shared__ unsigned short sHh[64*72];                   // h bf16, A-operand layout [n][k]
  __shared__ unsigned short sA[2][64*72], sA2[2][64*72];  // staged A/A2 bf16, dbuf
  __shared__ unsigned short sZ1[64*72], sZ2[64*72];       // zT[e][n'] bf16 (B-operand layout)
  __shared__ float sPart[64*17];
  int b = blockIdx.x, tid = threadIdx.x;
  int lane = tid & 63, w = tid >> 6, g = lane >> 4, c = lane & 15;
  int mt = w & 3, nt0 = (w >> 2) * 2;
  int e0_ = nt0*16 + c, e1_ = e0_ + 16;
  int mrow = mt*16 + 4*g;
  float itau[2] = {1.f/tau[e0_], 1.f/tau[e1_]};
  float apv_[2] = {Apv[e0_], Apv[e1_]};
  float bgv_[2] = {bg[e0_], bg[e1_]};
  FU wf[3][2][2][2];                      // [k3][tt][kt][hi/lo]
  #pragma unroll
  for (int k3 = 0; k3 < 3; ++k3)
    #pragma unroll
    for (int tt = 0; tt < 2; ++tt)
      #pragma unroll
      for (int kt = 0; kt < 2; ++kt) {
        int off = k3*4096 + ((nt0+tt)*16 + c)*64 + kt*32 + 8*g;
        wf[k3][tt][kt][0].q = *(const uint4*)(WTh + off);
        wf[k3][tt][kt][1].q = *(const uint4*)(WTl + off);
      }
  float hm[2][4];
  #pragma unroll
  for (int tt = 0; tt < 2; ++tt)
    #pragma unroll
    for (int r = 0; r < 4; ++r)
      hm[tt][r] = h0[(size_t)b*4096 + (mrow+r)*64 + (tt ? e1_ : e0_)];
  #pragma unroll
  for (int tt = 0; tt < 2; ++tt) {
    int e = tt ? e1_ : e0_;
    #pragma unroll
    for (int r = 0; r < 4; ++r)
      sHh[(mrow+r)*72 + e] = bf16_rn(hm[tt][r]);
  }
  {  // stage t=0 A/A2
    uint4 pa  = *(const uint4*)(Abf  + (size_t)b*64*4096 + tid*8);
    uint4 pa2 = *(const uint4*)(A2bf + (size_t)b*64*4096 + tid*8);
    int row = tid >> 3, k0 = (tid & 7) * 8;
    *(uint4*)&sA[0][row*72 + k0]  = pa;
    *(uint4*)&sA2[0][row*72 + k0] = pa2;
  }
  __syncthreads();
  #pragma unroll 1
  for (int t = 0; t < 64; ++t) {
    int cur = t & 1;
    size_t bt = (size_t)b*64 + t;
    int tn = (t < 63) ? t + 1 : t;
    uint4 pa  = *(const uint4*)(Abf  + ((size_t)b*64 + tn)*4096 + tid*8);
    uint4 pa2 = *(const uint4*)(A2bf + ((size_t)b*64 + tn)*4096 + tid*8);
    float gxv[2][4];
    {
      const float* gp = gxg + bt*4096;
      #pragma unroll
      for (int tt = 0; tt < 2; ++tt)
        #pragma unroll
        for (int r = 0; r < 4; ++r)
          gxv[tt][r] = gp[(mrow+r)*64 + (tt ? e1_ : e0_)];
    }
    // ---- z-phase: z1 = h@Wh1, z2 = h@Wh2 (h single-bf16, W hi/lo) ----
    FU ha[2];
    #pragma unroll
    for (int kt = 0; kt < 2; ++kt)
      ha[kt].q = *(const uint4*)&sHh[(mt*16 + c)*72 + kt*32 + 8*g];
    #pragma unroll
    for (int tt = 0; tt < 2; ++tt) {
      f32x4 a1 = {0.f, 0.f, 0.f, 0.f}, a2 = {0.f, 0.f, 0.f, 0.f};
      #pragma unroll
      for (int kt = 0; kt < 2; ++kt) {
        a1 = MFMA(ha[kt].v, wf[1][tt][kt][0].v, a1);
        a1 = MFMA(ha[kt].v, wf[1][tt][kt][1].v, a1);
        a2 = MFMA(ha[kt].v, wf[2][tt][kt][0].v, a2);
        a2 = MFMA(ha[kt].v, wf[2][tt][kt][1].v, a2);
      }
      int e = tt ? e1_ : e0_;
      ushort4 o1, o2;
      o1.x = bf16_rn(a1[0]); o1.y = bf16_rn(a1[1]); o1.z = bf16_rn(a1[2]); o1.w = bf16_rn(a1[3]);
      o2.x = bf16_rn(a2[0]); o2.y = bf16_rn(a2[1]); o2.z = bf16_rn(a2[2]); o2.w = bf16_rn(a2[3]);
      *(ushort4*)&sZ1[e*72 + mrow] = o1;
      *(ushort4*)&sZ2[e*72 + mrow] = o2;
    }
    __syncthreads();   // B1: sZ ready; sHh reads done
    // ---- gc-phase: gc = h@Wh0 + A@z1 + A2@z2 + gx + bg ----
    f32x4 acc[2] = {{0.f,0.f,0.f,0.f}, {0.f,0.f,0.f,0.f}};
    #pragma unroll
    for (int kt = 0; kt < 2; ++kt) {
      FU aA, aA2;
      int ao = (mt*16 + c)*72 + kt*32 + 8*g;
      aA.q  = *(const uint4*)&sA[cur][ao];
      aA2.q = *(const uint4*)&sA2[cur][ao];
      #pragma unroll
      for (int tt = 0; tt < 2; ++tt) {
        int e = tt ? e1_ : e0_;
        acc[tt] = MFMA(ha[kt].v, wf[0][tt][kt][0].v, acc[tt]);
        acc[tt] = MFMA(ha[kt].v, wf[0][tt][kt][1].v, acc[tt]);
        FU z1f, z2f;
        z1f.q = *(const uint4*)&sZ1[e*72 + kt*32 + 8*g];
        z2f.q = *(const uint4*)&sZ2[e*72 + kt*32 + 8*g];
        acc[tt] = MFMA(aA.v,  z1f.v, acc[tt]);
        acc[tt] = MFMA(aA2.v, z2f.v, acc[tt]);
      }
    }
    // h update + write-back + mean partials
    #pragma unroll
    for (int tt = 0; tt < 2; ++tt) {
      int e = tt ? e1_ : e0_;
      float ps = 0.f;
      #pragma unroll
      for (int r = 0; r < 4; ++r) {
        float gc = acc[tt][r] + gxv[tt][r] + bgv_[tt];
        float f = tanh_f(gc);
        float h_ = hm[tt][r];
        float hn = h_ + DT_C * (-(itau[tt] + f) * h_ + f * apv_[tt]);
        hm[tt][r] = hn;
        ps += hn;
        sHh[(mrow+r)*72 + e] = bf16_rn(hn);
      }
      sPart[e*17 + mt*4 + g] = ps;
    }
    {  // staging write for next step
      int row = tid >> 3, k0 = (tid & 7) * 8;
      *(uint4*)&sA[cur^1][row*72 + k0]  = pa;
      *(uint4*)&sA2[cur^1][row*72 + k0] = pa2;
    }
    __syncthreads();   // B3: h/sZ-consumed/staging/sPart visible
    if (lane < 8) {    // distributed mean: wave w reduces e = w*8 + lane
      int e = w*8 + lane;
      float s = 0.f;
      #pragma unroll
      for (int j = 0; j < 16; ++j) s += sPart[e*17 + j];
      mout[bt*64 + e] = s * (1.0f / 64.0f);
    }
  }
  // final_h (fp32 master copy)
  #pragma unroll
  for (int tt = 0; tt < 2; ++tt)
    #pragma unroll
    for (int r = 0; r < 4; ++r)
      out[512 + (size_t)b*4096 + (mrow+r)*64 + (tt ? e1_ : e0_)] = hm[tt][r];
}

// ---- decoder MLP for all (b,t) in parallel ----
__global__ __launch_bounds__(128) void dec_k(const float* __restrict__ mout,
                                             const float* __restrict__ Wd1, const float* __restrict__ bd1,
                                             const float* __restrict__ Wd2, const float* __restrict__ bd2,
                                             const float* __restrict__ Wd3, const float* __restrict__ bd3,
                                             float* __restrict__ out) {
  __shared__ float sm[64], sd1[128], sd2[64];
  int bt = blockIdx.x, tid = threadIdx.x;
  if (tid < 64) sm[tid] = mout[(size_t)bt*64 + tid];
  __syncthreads();
  {
    float a = bd1[tid];
    #pragma unroll 8
    for (int e = 0; e < 64; ++e) a += sm[e] * Wd1[e*128 + tid];
    sd1[tid] = fmaxf(a, 0.f);
  }
  __syncthreads();
  if (tid < 64) {
    float a = bd2[tid];
    #pragma unroll 8
    for (int i = 0; i < 128; ++i) a += sd1[i] * Wd2[i*64 + tid];
    sd2[tid] = fmaxf(a, 0.f);
  }
  __syncthreads();
  if (tid < 64) {
    float p = sd2[tid] * Wd3[tid];
    #pragma unroll
    for (int off = 32; off > 0; off >>= 1) p += __shfl_down(p, off, 64);
    if (tid == 0) out[bt] = p + bd3[0];
  }
}

extern "C" void kernel_launch(void* const* d_in, const int* in_sizes, int n_in,
                              void* d_out, int out_size, void* d_ws, size_t ws_size,
                              hipStream_t stream) {
  const float* frames = (const float*)d_in[0];
  const float* adj    = (const float*)d_in[1];
  const float* h0     = (const float*)d_in[2];
  const float* Wc1 = (const float*)d_in[3];  const float* bc1 = (const float*)d_in[4];
  const float* Wc2 = (const float*)d_in[5];  const float* bc2 = (const float*)d_in[6];
  const float* Wc3 = (const float*)d_in[7];  const float* bc3 = (const float*)d_in[8];
  const float* We  = (const float*)d_in[9];  const float* be  = (const float*)d_in[10];
  const float* Wh  = (const float*)d_in[11]; const float* Wx  = (const float*)d_in[12];
  const float* bg  = (const float*)d_in[13]; const float* tau = (const float*)d_in[14];
  const float* Ap  = (const float*)d_in[15];
  const float* Wd1 = (const float*)d_in[16]; const float* bd1 = (const float*)d_in[17];
  const float* Wd2 = (const float*)d_in[18]; const float* bd2 = (const float*)d_in[19];
  const float* Wd3 = (const float*)d_in[20]; const float* bd3 = (const float*)d_in[21];

  float* ws = (float*)d_ws;
  // Workspace map (float offsets; validated 25,165,824-float budget).
  // Phase 1 (conv chain):
  //   c1h  [0,          8,388,608)   16.78M halves -- dead after conv2m
  //   c1l  [8,388,608, 16,777,216)   16.78M halves -- dead after conv2m
  //   c2h  [16,777,216, 20,971,520)   8.39M halves -- dead after conv3m
  //   weights [20,971,520, ~21,076,000): W2h/W2l/W3h/W3l/WTh/WTl (persist)
  // Phase 2 (reuses dead c1 regions):
  //   c3 [0, 4.19M)  node [4.19M, 6.29M)  gx [6.29M, 8.39M)
  //   Abf [8.39M, 9.44M)  A2bf [9.44M, 10.49M)  mo [10.49M, ..)
  unsigned short* c1h = (unsigned short*)(ws);
  unsigned short* c1l = (unsigned short*)(ws + 8388608);
  unsigned short* c2h = (unsigned short*)(ws + 16777216);
  unsigned short* W2h = (unsigned short*)(ws + 20971520);
  unsigned short* W2l = (unsigned short*)(ws + 20980736);
  unsigned short* W3h = (unsigned short*)(ws + 20989952);
  unsigned short* W3l = (unsigned short*)(ws + 21026816);
  unsigned short* WTh = (unsigned short*)(ws + 21063680);
  unsigned short* WTl = (unsigned short*)(ws + 21069824);
  float* c3   = ws;
  float* node = ws + 4194304;
  float* gx   = ws + 6291456;
  unsigned short* Abf  = (unsigned short*)(ws + 8388608);
  unsigned short* A2bf = (unsigned short*)(ws + 9437184);
  float* mo   = ws + 10485760;
  float* out  = (float*)d_out;

  wprep_k <<<408, 256, 0, stream>>>(Wc2, Wc3, Wh, W2h, W2l, W3h, W3l, WTh, WTl);
  conv1_k <<<512, 256, 0, stream>>>(frames, Wc1, bc1, c1h, c1l);
  conv2m_k<<<512, 256, 0, stream>>>(c1h, c1l, W2h, W2l, bc2, c2h);
  conv3m_k<<<512, 256, 0, stream>>>(c2h, W3h, W3l, bc3, c3);
  embed_k <<<512, 256, 0, stream>>>(c3, We, be, node);
  prep_k  <<<512, 256, 0, stream>>>(adj, node, Wx, Abf, A2bf, gx);
  seq2_k  <<<8,   512, 0, stream>>>(Abf, A2bf, gx, h0, WTh, WTl, bg, tau, Ap, mo, out);
  dec_k   <<<512, 128, 0, stream>>>(mo, Wd1, bd1, Wd2, bd2, Wd3, bd3, out);
}

// Round 7
// 337.324 us; speedup vs baseline: 2.7939x; 1.0273x over previous
//
#include <hip/hip_runtime.h>
#include <hip/hip_bf16.h>

#define SH 68            // padded LDS row stride (floats) for fp32 prep kernels
#define DT_C 0.1f

typedef short bfrag __attribute__((ext_vector_type(8)));     // 8 bf16
typedef _Float16 hfrag __attribute__((ext_vector_type(8)));  // 8 fp16
typedef float f32x4 __attribute__((ext_vector_type(4)));

union FU { bfrag v; unsigned short s[8]; uint4 q; };
union HU { hfrag v; unsigned short s[8]; uint4 q; };

__device__ __forceinline__ unsigned short bf16_rn(float x) {
  union { float f; unsigned u; } v; v.f = x;
  unsigned r = v.u + 0x7fffu + ((v.u >> 16) & 1u);
  return (unsigned short)(r >> 16);
}
__device__ __forceinline__ float bf16_tof(unsigned short h) {
  union { unsigned u; float f; } v; v.u = ((unsigned)h) << 16; return v.f;
}
// native RNE f32->bf16 (compiler can fuse pairs into v_cvt_pk_bf16_f32)
__device__ __forceinline__ unsigned short bfu(float x) {
  union { __hip_bfloat16 b; unsigned short u; } cv;
  cv.b = __float2bfloat16(x);
  return cv.u;
}
__device__ __forceinline__ float tanh_f(float x) {
  return 1.0f - 2.0f / (__expf(2.0f * x) + 1.0f);
}
// fp16 hi/lo split of a float
__device__ __forceinline__ void h16split(float v, unsigned short& hu, unsigned short& lu) {
  union { _Float16 h; unsigned short u; } a, b;
  a.h = (_Float16)v;
  b.h = (_Float16)(v - (float)a.h);
  hu = a.u; lu = b.u;
}
__device__ __forceinline__ unsigned short h16hi(float v) {
  union { _Float16 h; unsigned short u; } a; a.h = (_Float16)v; return a.u;
}

// ---- fp32 4x4-block 64-K matmul helper (A stride SH; acc += A[n0..][*] * B[*][e0..]) ----
__device__ __forceinline__ void mm16(const float* __restrict__ A,
                                     const float* __restrict__ B, int sb,
                                     float acc[4][4], int n0, int e0) {
  #pragma unroll 2
  for (int k = 0; k < 64; ++k) {
    float a0 = A[(n0+0)*SH+k];
    float a1 = A[(n0+1)*SH+k];
    float a2 = A[(n0+2)*SH+k];
    float a3 = A[(n0+3)*SH+k];
    const float4 bv = *(const float4*)(B + k*sb + e0);
    acc[0][0]+=a0*bv.x; acc[0][1]+=a0*bv.y; acc[0][2]+=a0*bv.z; acc[0][3]+=a0*bv.w;
    acc[1][0]+=a1*bv.x; acc[1][1]+=a1*bv.y; acc[1][2]+=a1*bv.z; acc[1][3]+=a1*bv.w;
    acc[2][0]+=a2*bv.x; acc[2][1]+=a2*bv.y; acc[2][2]+=a2*bv.z; acc[2][3]+=a2*bv.w;
    acc[3][0]+=a3*bv.x; acc[3][1]+=a3*bv.y; acc[3][2]+=a3*bv.z; acc[3][3]+=a3*bv.w;
  }
}

// ---- fused weight prep: Wc2 -> W2 fp16 hi/lo [oc][pos][ic] (18432),
//      Wc3 -> W3 fp16 hi/lo [oc][pos][ic] (73728), Wh -> WT bf16 hi/lo [k3][dout][din] (12288)
__global__ __launch_bounds__(256) void wprep_k(const float* __restrict__ Wc2,
                                               const float* __restrict__ Wc3,
                                               const float* __restrict__ Wh,
                                               unsigned short* __restrict__ W2h,
                                               unsigned short* __restrict__ W2l,
                                               unsigned short* __restrict__ W3h,
                                               unsigned short* __restrict__ W3l,
                                               unsigned short* __restrict__ WTh,
                                               unsigned short* __restrict__ WTl) {
  int i = blockIdx.x * 256 + threadIdx.x;
  if (i < 18432) {
    int oc = i / 288, rem = i % 288, pos = rem >> 5, ic = rem & 31;
    float v = Wc2[oc*288 + ic*9 + pos];
    h16split(v, W2h[i], W2l[i]);
  } else if (i < 18432 + 73728) {
    int j = i - 18432;
    int oc = j / 576, rem = j % 576, pos = rem >> 6, ic = rem & 63;
    float v = Wc3[oc*576 + ic*9 + pos];
    h16split(v, W3h[j], W3l[j]);
  } else if (i < 18432 + 73728 + 12288) {
    int j = i - 92160;
    int k3 = j >> 12, rem = j & 4095, din = rem >> 6, dout = rem & 63;
    float v = Wh[j];
    unsigned short hi = bf16_rn(v);
    WTh[k3*4096 + dout*64 + din] = hi;
    WTl[k3*4096 + dout*64 + din] = bf16_rn(v - bf16_tof(hi));
  }
}

// ---- conv1: [512,3,64,64] -> fp16 hi/lo planes in conv2-staging layout ----
__global__ __launch_bounds__(256) void conv1_k(const float* __restrict__ frames,
                                               const float* __restrict__ W,
                                               const float* __restrict__ bias,
                                               unsigned short* __restrict__ c1h,
                                               unsigned short* __restrict__ c1l) {
  __shared__ __align__(16) float sIn[12288];
  int bt = blockIdx.x, tid = threadIdx.x;
  const float4* src = (const float4*)(frames + (size_t)bt * 12288);
  for (int i = tid; i < 3072; i += 256) ((float4*)sIn)[i] = src[i];
  __syncthreads();
  for (int p = tid; p < 1024; p += 256) {
    int ho = p >> 5, wo = p & 31, hi0 = ho*2-1, wi0 = wo*2-1;
    int obase = (((ho*2 + (wo&1))*16 + (wo>>1)))*8;
    for (int ocb = 0; ocb < 4; ++ocb) {
      float acc[8];
      #pragma unroll
      for (int j = 0; j < 8; ++j) acc[j] = bias[ocb*8+j];
      for (int ic = 0; ic < 3; ++ic) {
        float win[9];
        #pragma unroll
        for (int kh = 0; kh < 3; ++kh) {
          int hi = hi0 + kh;
          #pragma unroll
          for (int kw = 0; kw < 3; ++kw) {
            int wi = wi0 + kw;
            win[kh*3+kw] = (hi>=0 && hi<64 && wi>=0 && wi<64) ? sIn[ic*4096 + hi*64 + wi] : 0.f;
          }
        }
        #pragma unroll
        for (int j = 0; j < 8; ++j) {
          const float* wp = W + (size_t)(ocb*8+j)*27 + ic*9;
          #pragma unroll
          for (int k = 0; k < 9; ++k) acc[j] += win[k] * wp[k];
        }
      }
      ushort hh[8], ll[8];
      #pragma unroll
      for (int j = 0; j < 8; ++j) h16split(fmaxf(acc[j], 0.f), hh[j], ll[j]);
      size_t dst = (size_t)bt*32768 + ocb*8192 + obase;
      *(uint4*)&c1h[dst] = *(uint4*)hh;
      *(uint4*)&c1l[dst] = *(uint4*)ll;
    }
  }
}

#define MFMAH(a, bb, cc) __builtin_amdgcn_mfma_f32_16x16x32_f16((a), (bb), (cc), 0, 0, 0)

// ---- conv2 implicit-GEMM MFMA: M=256 pix, N=64 oc, K=288 (9 pos x 32 ic) ----
__global__ __launch_bounds__(256) void conv2m_k(const unsigned short* __restrict__ c1h,
                                                const unsigned short* __restrict__ c1l,
                                                const unsigned short* __restrict__ W2h,
                                                const unsigned short* __restrict__ W2l,
                                                const float* __restrict__ bias,
                                                unsigned short* __restrict__ c2h) {
  __shared__ __align__(16) unsigned short sH[32768], sL[32768];
  int bt = blockIdx.x, tid = threadIdx.x;
  {
    const uint4* gh = (const uint4*)(c1h + (size_t)bt*32768);
    const uint4* gl = (const uint4*)(c1l + (size_t)bt*32768);
    for (int i = tid; i < 4096; i += 256) { ((uint4*)sH)[i] = gh[i]; ((uint4*)sL)[i] = gl[i]; }
  }
  __syncthreads();
  int lane = tid & 63, w = tid >> 6, g = lane >> 4, c = lane & 15;
  f32x4 acc[4][4] = {};
  const uint4 z4 = make_uint4(0,0,0,0);
  #pragma unroll
  for (int pos = 0; pos < 9; ++pos) {
    const int kh = pos / 3, kw = pos % 3;
    HU Ah[4], Al[4];
    #pragma unroll
    for (int m = 0; m < 4; ++m) {
      int pix = w*64 + m*16 + c;
      int ho = pix >> 4, wo = pix & 15;
      int hi = 2*ho - 1 + kh, wi = 2*wo - 1 + kw;
      bool ok = (hi >= 0) & (wi >= 0);
      int hic = ok ? hi : 0, wic = ok ? wi : 0;
      int a = (((g*32 + hic)*2 + (wic & 1))*16 + (wic >> 1))*8;
      uint4 vh = *(const uint4*)&sH[a];
      uint4 vl = *(const uint4*)&sL[a];
      Ah[m].q = ok ? vh : z4;
      Al[m].q = ok ? vl : z4;
    }
    HU Bh[4], Bl[4];
    #pragma unroll
    for (int n = 0; n < 4; ++n) {
      int off = (n*16 + c)*288 + pos*32 + g*8;
      Bh[n].q = *(const uint4*)(W2h + off);
      Bl[n].q = *(const uint4*)(W2l + off);
    }
    #pragma unroll
    for (int m = 0; m < 4; ++m)
      #pragma unroll
      for (int n = 0; n < 4; ++n) {
        acc[m][n] = MFMAH(Ah[m].v, Bh[n].v, acc[m][n]);
        acc[m][n] = MFMAH(Al[m].v, Bh[n].v, acc[m][n]);
        acc[m][n] = MFMAH(Ah[m].v, Bl[n].v, acc[m][n]);
      }
  }
  #pragma unroll
  for (int n = 0; n < 4; ++n) {
    int oc = n*16 + c;
    float bv = bias[oc];
    int ks3 = oc >> 3, il = oc & 7;
    #pragma unroll
    for (int m = 0; m < 4; ++m) {
      #pragma unroll
      for (int r = 0; r < 4; ++r) {
        int pix = w*64 + m*16 + 4*g + r;
        int ho = pix >> 4, wo = pix & 15;
        float v = fmaxf(acc[m][n][r] + bv, 0.f);
        size_t dst = (size_t)bt*16384 + ((((ks3*16 + ho)*2 + (wo&1))*8 + (wo>>1)))*8 + il;
        c2h[dst] = h16hi(v);
      }
    }
  }
}

// ---- conv3 implicit-GEMM MFMA: M=64 pix, N=128 oc, K=576 -> fp32 c3 ----
__global__ __launch_bounds__(256) void conv3m_k(const unsigned short* __restrict__ c2h,
                                                const unsigned short* __restrict__ W3h,
                                                const unsigned short* __restrict__ W3l,
                                                const float* __restrict__ bias,
                                                float* __restrict__ c3) {
  __shared__ __align__(16) unsigned short sH[16384];
  int bt = blockIdx.x, tid = threadIdx.x;
  {
    const uint4* gh = (const uint4*)(c2h + (size_t)bt*16384);
    for (int i = tid; i < 2048; i += 256) ((uint4*)sH)[i] = gh[i];
  }
  __syncthreads();
  int lane = tid & 63, w = tid >> 6, g = lane >> 4, c = lane & 15;
  f32x4 acc[8] = {};
  const uint4 z4 = make_uint4(0,0,0,0);
  int pix = w*16 + c;
  int ho = pix >> 3, wo = pix & 7;
  #pragma unroll
  for (int pos = 0; pos < 9; ++pos) {
    const int kh = pos / 3, kw = pos % 3;
    int hi = 2*ho - 1 + kh, wi = 2*wo - 1 + kw;
    bool ok = (hi >= 0) & (wi >= 0);
    int hic = ok ? hi : 0, wic = ok ? wi : 0;
    #pragma unroll
    for (int ih = 0; ih < 2; ++ih) {
      int icg = ih*4 + g;
      int a = ((((icg*16 + hic)*2 + (wic & 1))*8 + (wic >> 1)))*8;
      HU Ah;
      uint4 vh = *(const uint4*)&sH[a];
      Ah.q = ok ? vh : z4;
      #pragma unroll
      for (int n = 0; n < 8; ++n) {
        int off = (n*16 + c)*576 + pos*64 + ih*32 + g*8;
        HU Bh, Bl;
        Bh.q = *(const uint4*)(W3h + off);
        Bl.q = *(const uint4*)(W3l + off);
        acc[n] = MFMAH(Ah.v, Bh.v, acc[n]);
        acc[n] = MFMAH(Ah.v, Bl.v, acc[n]);
      }
    }
  }
  #pragma unroll
  for (int n = 0; n < 8; ++n) {
    int oc = n*16 + c;
    float bv = bias[oc];
    #pragma unroll
    for (int r = 0; r < 4; ++r) {
      int po = w*16 + 4*g + r;
      c3[(size_t)(bt*128 + oc)*64 + po] = fmaxf(acc[n][r] + bv, 0.f);
    }
  }
}

// ---- embed: node[bt,n,e] = sum_c c3[bt,c,n] * We[c,e] + be[e] ----
__global__ __launch_bounds__(256) void embed_k(const float* __restrict__ c3,
                                               const float* __restrict__ We,
                                               const float* __restrict__ be,
                                               float* __restrict__ node) {
  __shared__ float sF[64*133];
  __shared__ __align__(16) float sWe[8192];
  int bt = blockIdx.x, tid = threadIdx.x;
  const float* src = c3 + (size_t)bt * 8192;
  for (int i = tid; i < 8192; i += 256) sF[(i & 63)*133 + (i >> 6)] = src[i];
  const float4* w4 = (const float4*)We;
  for (int i = tid; i < 2048; i += 256) ((float4*)sWe)[i] = w4[i];
  __syncthreads();
  int lane = tid & 63, w = tid >> 6, nsub = lane >> 4, eb = lane & 15;
  int n0 = w*16 + nsub*4, e0 = eb*4;
  float acc[4][4];
  #pragma unroll
  for (int jj = 0; jj < 4; ++jj)
    #pragma unroll
    for (int ee = 0; ee < 4; ++ee) acc[jj][ee] = be[e0+ee];
  for (int c = 0; c < 128; ++c) {
    float a0 = sF[(n0+0)*133+c];
    float a1 = sF[(n0+1)*133+c];
    float a2 = sF[(n0+2)*133+c];
    float a3 = sF[(n0+3)*133+c];
    const float4 bv = *(const float4*)&sWe[c*64 + e0];
    acc[0][0]+=a0*bv.x; acc[0][1]+=a0*bv.y; acc[0][2]+=a0*bv.z; acc[0][3]+=a0*bv.w;
    acc[1][0]+=a1*bv.x; acc[1][1]+=a1*bv.y; acc[1][2]+=a1*bv.z; acc[1][3]+=a1*bv.w;
    acc[2][0]+=a2*bv.x; acc[2][1]+=a2*bv.y; acc[2][2]+=a2*bv.z; acc[2][3]+=a2*bv.w;
    acc[3][0]+=a3*bv.x; acc[3][1]+=a3*bv.y; acc[3][2]+=a3*bv.z; acc[3][3]+=a3*bv.w;
  }
  float4* nd = (float4*)(node + (size_t)bt * 4096);
  #pragma unroll
  for (int jj = 0; jj < 4; ++jj)
    nd[(n0+jj)*16 + eb] = make_float4(acc[jj][0], acc[jj][1], acc[jj][2], acc[jj][3]);
}

// ---- prep: A2=A@A ; gx = x@Wx0 + A@(x@Wx1) + A2@(x@Wx2); emit bf16 A, A2 + fp32 gx ----
__global__ __launch_bounds__(256) void prep_k(const float* __restrict__ adj,
                                              const float* __restrict__ node,
                                              const float* __restrict__ Wx,
                                              unsigned short* __restrict__ Abf,
                                              unsigned short* __restrict__ A2bf,
                                              float* __restrict__ gxg) {
  __shared__ __align__(16) float sA[64*SH], sA2[64*SH], sN[64*SH], sZ[64*SH];
  __shared__ __align__(16) float sWx[12288];
  int bt = blockIdx.x, tid = threadIdx.x;
  {
    const float4* a4 = (const float4*)(adj + (size_t)bt * 4096);
    const float4* n4 = (const float4*)(node + (size_t)bt * 4096);
    for (int i = tid; i < 1024; i += 256) {
      int r = i >> 4, c = (i & 15) * 4;
      *(float4*)&sA[r*SH+c] = a4[i];
      *(float4*)&sN[r*SH+c] = n4[i];
    }
    const float4* w4 = (const float4*)Wx;
    for (int i = tid; i < 3072; i += 256) ((float4*)sWx)[i] = w4[i];
  }
  __syncthreads();
  int lane = tid & 63, w = tid >> 6, nsub = lane >> 4, eb = lane & 15;
  int n0 = w*16 + nsub*4, e0 = eb*4;
  float4* gxout = (float4*)(gxg + (size_t)bt * 4096);
  for (int i = tid; i < 1024; i += 256) {
    int r = i >> 4, c0 = (i & 15) * 4;
    ushort4 o;
    o.x = bf16_rn(sA[r*SH+c0+0]); o.y = bf16_rn(sA[r*SH+c0+1]);
    o.z = bf16_rn(sA[r*SH+c0+2]); o.w = bf16_rn(sA[r*SH+c0+3]);
    *(ushort4*)&Abf[(size_t)bt*4096 + r*64 + c0] = o;
  }
  {
    float a2t[4][4] = {};
    mm16(sA, sA, SH, a2t, n0, e0);
    #pragma unroll
    for (int jj = 0; jj < 4; ++jj) {
      *(float4*)&sA2[(n0+jj)*SH+e0] = make_float4(a2t[jj][0], a2t[jj][1], a2t[jj][2], a2t[jj][3]);
      ushort4 o;
      o.x = bf16_rn(a2t[jj][0]); o.y = bf16_rn(a2t[jj][1]);
      o.z = bf16_rn(a2t[jj][2]); o.w = bf16_rn(a2t[jj][3]);
      *(ushort4*)&A2bf[(size_t)bt*4096 + (n0+jj)*64 + e0] = o;
    }
  }
  {
    float t[4][4] = {};
    mm16(sN, sWx + 4096, 64, t, n0, e0);       // z1 = x @ Wx1
    #pragma unroll
    for (int jj = 0; jj < 4; ++jj)
      *(float4*)&sZ[(n0+jj)*SH+e0] = make_float4(t[jj][0], t[jj][1], t[jj][2], t[jj][3]);
  }
  __syncthreads();
  float gx[4][4] = {};
  mm16(sA, sZ, SH, gx, n0, e0);                // gx = A @ z1
  __syncthreads();
  {
    float t[4][4] = {};
    mm16(sN, sWx + 8192, 64, t, n0, e0);       // z2 = x @ Wx2
    #pragma unroll
    for (int jj = 0; jj < 4; ++jj)
      *(float4*)&sZ[(n0+jj)*SH+e0] = make_float4(t[jj][0], t[jj][1], t[jj][2], t[jj][3]);
  }
  __syncthreads();
  mm16(sA2, sZ, SH, gx, n0, e0);               // gx += A2 @ z2
  mm16(sN, sWx, 64, gx, n0, e0);               // gx += x @ Wx0
  #pragma unroll
  for (int jj = 0; jj < 4; ++jj)
    gxout[(n0+jj)*16 + eb] = make_float4(gx[jj][0], gx[jj][1], gx[jj][2], gx[jj][3]);
}

#define MFMA(a, bb, cc) __builtin_amdgcn_mfma_f32_16x16x32_bf16((a), (bb), (cc), 0, 0, 0)

// ---- sequential recurrence via MFMA: one block per batch chain, 16 waves ----
// Wave (mt, nt) owns output tile rows mt*16..+15, cols nt*16..+15.
// Precision: Wh bf16 hi/lo (static, correlated); h/z/A/A2 single-bf16 (per-step
// uncorrelated rounding); h master state fp32 in registers.
__global__ __launch_bounds__(1024, 4) void seq2_k(
    const unsigned short* __restrict__ Abf, const unsigned short* __restrict__ A2bf,
    const float* __restrict__ gxg, const float* __restrict__ h0,
    const unsigned short* __restrict__ WTh, const unsigned short* __restrict__ WTl,
    const float* __restrict__ bg, const float* __restrict__ tau, const float* __restrict__ Apv,
    float* __restrict__ mout, float* __restrict__ out) {
  __shared__ unsigned short sHh[64*72];                   // h bf16, [n][k] A-operand layout
  __shared__ unsigned short sA[2][64*72], sA2[2][64*72];  // staged A/A2 bf16, dbuf
  __shared__ unsigned short sZ1[64*72], sZ2[64*72];       // zT[e][n'] bf16
  __shared__ float sPart[64*17];
  int b = blockIdx.x, tid = threadIdx.x;
  int lane = tid & 63, w = tid >> 6, g = lane >> 4, c = lane & 15;
  int mt = w & 3, nt = w >> 2;
  int e = nt*16 + c;
  int mrow = mt*16 + 4*g;
  float itau = 1.f/tau[e], apv = Apv[e], bgv = bg[e];
  FU wf[3][2][2];                          // [k3][kt][hi/lo]
  #pragma unroll
  for (int k3 = 0; k3 < 3; ++k3)
    #pragma unroll
    for (int kt = 0; kt < 2; ++kt) {
      int off = k3*4096 + e*64 + kt*32 + 8*g;
      wf[k3][kt][0].q = *(const uint4*)(WTh + off);
      wf[k3][kt][1].q = *(const uint4*)(WTl + off);
    }
  float hm[4];
  #pragma unroll
  for (int r = 0; r < 4; ++r) hm[r] = h0[(size_t)b*4096 + (mrow+r)*64 + e];
  #pragma unroll
  for (int r = 0; r < 4; ++r) sHh[(mrow+r)*72 + e] = bfu(hm[r]);
  {  // stage t=0 A/A2 (1024 threads x 4 halves = 4096)
    int row = tid >> 4, k0 = (tid & 15) * 4;
    *(uint2*)&sA[0][row*72 + k0]  = *(const uint2*)(Abf  + (size_t)b*64*4096 + tid*4);
    *(uint2*)&sA2[0][row*72 + k0] = *(const uint2*)(A2bf + (size_t)b*64*4096 + tid*4);
  }
  __syncthreads();
  #pragma unroll 1
  for (int t = 0; t < 64; ++t) {
    int cur = t & 1;
    size_t bt = (size_t)b*64 + t;
    int tn = (t < 63) ? t + 1 : t;
    uint2 pa  = *(const uint2*)(Abf  + ((size_t)b*64 + tn)*4096 + tid*4);
    uint2 pa2 = *(const uint2*)(A2bf + ((size_t)b*64 + tn)*4096 + tid*4);
    float gxv[4];
    {
      const float* gp = gxg + bt*4096;
      #pragma unroll
      for (int r = 0; r < 4; ++r) gxv[r] = gp[(mrow+r)*64 + e];
    }
    // ---- z-phase: z1 = h@Wh1, z2 = h@Wh2 ----
    FU ha[2];
    #pragma unroll
    for (int kt = 0; kt < 2; ++kt)
      ha[kt].q = *(const uint4*)&sHh[(mt*16 + c)*72 + kt*32 + 8*g];
    f32x4 a1 = {0.f,0.f,0.f,0.f}, a2 = {0.f,0.f,0.f,0.f};
    #pragma unroll
    for (int kt = 0; kt < 2; ++kt) {
      a1 = MFMA(ha[kt].v, wf[1][kt][0].v, a1);
      a1 = MFMA(ha[kt].v, wf[1][kt][1].v, a1);
      a2 = MFMA(ha[kt].v, wf[2][kt][0].v, a2);
      a2 = MFMA(ha[kt].v, wf[2][kt][1].v, a2);
    }
    {
      ushort4 o1, o2;
      o1.x = bfu(a1[0]); o1.y = bfu(a1[1]); o1.z = bfu(a1[2]); o1.w = bfu(a1[3]);
      o2.x = bfu(a2[0]); o2.y = bfu(a2[1]); o2.z = bfu(a2[2]); o2.w = bfu(a2[3]);
      *(ushort4*)&sZ1[e*72 + mrow] = o1;
      *(ushort4*)&sZ2[e*72 + mrow] = o2;
    }
    __syncthreads();   // B1: sZ ready; sHh reads done
    // ---- gc-phase: gc = h@Wh0 + A@z1 + A2@z2 + gx + bg ----
    f32x4 acc = {0.f,0.f,0.f,0.f};
    #pragma unroll
    for (int kt = 0; kt < 2; ++kt) {
      FU aA, aA2, z1f, z2f;
      int ao = (mt*16 + c)*72 + kt*32 + 8*g;
      aA.q  = *(const uint4*)&sA[cur][ao];
      aA2.q = *(const uint4*)&sA2[cur][ao];
      z1f.q = *(const uint4*)&sZ1[e*72 + kt*32 + 8*g];
      z2f.q = *(const uint4*)&sZ2[e*72 + kt*32 + 8*g];
      acc = MFMA(ha[kt].v, wf[0][kt][0].v, acc);
      acc = MFMA(ha[kt].v, wf[0][kt][1].v, acc);
      acc = MFMA(aA.v,  z1f.v, acc);
      acc = MFMA(aA2.v, z2f.v, acc);
    }
    // h update + write-back + mean partials
    float ps = 0.f;
    #pragma unroll
    for (int r = 0; r < 4; ++r) {
      float gc = acc[r] + gxv[r] + bgv;
      float f = tanh_f(gc);
      float hn = hm[r] + DT_C * (-(itau + f) * hm[r] + f * apv);
      hm[r] = hn;
      ps += hn;
      sHh[(mrow+r)*72 + e] = bfu(hn);
    }
    sPart[e*17 + mt*4 + g] = ps;
    {  // staging write for next step
      int row = tid >> 4, k0 = (tid & 15) * 4;
      *(uint2*)&sA[cur^1][row*72 + k0]  = pa;
      *(uint2*)&sA2[cur^1][row*72 + k0] = pa2;
    }
    __syncthreads();   // B2: h/staging/sPart visible
    if (lane < 4) {    // distributed mean: wave w reduces e = w*4 + lane
      int ee = w*4 + lane;
      float s = 0.f;
      #pragma unroll
      for (int j = 0; j < 16; ++j) s += sPart[ee*17 + j];
      mout[bt*64 + ee] = s * (1.0f / 64.0f);
    }
  }
  // final_h (fp32 master copy)
  #pragma unroll
  for (int r = 0; r < 4; ++r)
    out[512 + (size_t)b*4096 + (mrow+r)*64 + e] = hm[r];
}

// ---- decoder MLP for all (b,t) in parallel ----
__global__ __launch_bounds__(128) void dec_k(const float* __restrict__ mout,
                                             const float* __restrict__ Wd1, const float* __restrict__ bd1,
                                             const float* __restrict__ Wd2, const float* __restrict__ bd2,
                                             const float* __restrict__ Wd3, const float* __restrict__ bd3,
                                             float* __restrict__ out) {
  __shared__ float sm[64], sd1[128], sd2[64];
  int bt = blockIdx.x, tid = threadIdx.x;
  if (tid < 64) sm[tid] = mout[(size_t)bt*64 + tid];
  __syncthreads();
  {
    float a = bd1[tid];
    #pragma unroll 8
    for (int e = 0; e < 64; ++e) a += sm[e] * Wd1[e*128 + tid];
    sd1[tid] = fmaxf(a, 0.f);
  }
  __syncthreads();
  if (tid < 64) {
    float a = bd2[tid];
    #pragma unroll 8
    for (int i = 0; i < 128; ++i) a += sd1[i] * Wd2[i*64 + tid];
    sd2[tid] = fmaxf(a, 0.f);
  }
  __syncthreads();
  if (tid < 64) {
    float p = sd2[tid] * Wd3[tid];
    #pragma unroll
    for (int off = 32; off > 0; off >>= 1) p += __shfl_down(p, off, 64);
    if (tid == 0) out[bt] = p + bd3[0];
  }
}

extern "C" void kernel_launch(void* const* d_in, const int* in_sizes, int n_in,
                              void* d_out, int out_size, void* d_ws, size_t ws_size,
                              hipStream_t stream) {
  const float* frames = (const float*)d_in[0];
  const float* adj    = (const float*)d_in[1];
  const float* h0     = (const float*)d_in[2];
  const float* Wc1 = (const float*)d_in[3];  const float* bc1 = (const float*)d_in[4];
  const float* Wc2 = (const float*)d_in[5];  const float* bc2 = (const float*)d_in[6];
  const float* Wc3 = (const float*)d_in[7];  const float* bc3 = (const float*)d_in[8];
  const float* We  = (const float*)d_in[9];  const float* be  = (const float*)d_in[10];
  const float* Wh  = (const float*)d_in[11]; const float* Wx  = (const float*)d_in[12];
  const float* bg  = (const float*)d_in[13]; const float* tau = (const float*)d_in[14];
  const float* Ap  = (const float*)d_in[15];
  const float* Wd1 = (const float*)d_in[16]; const float* bd1 = (const float*)d_in[17];
  const float* Wd2 = (const float*)d_in[18]; const float* bd2 = (const float*)d_in[19];
  const float* Wd3 = (const float*)d_in[20]; const float* bd3 = (const float*)d_in[21];

  float* ws = (float*)d_ws;
  // Workspace map (float offsets; 25,165,824-float budget) — validated R5.
  unsigned short* c1h = (unsigned short*)(ws);
  unsigned short* c1l = (unsigned short*)(ws + 8388608);
  unsigned short* c2h = (unsigned short*)(ws + 16777216);
  unsigned short* W2h = (unsigned short*)(ws + 20971520);
  unsigned short* W2l = (unsigned short*)(ws + 20980736);
  unsigned short* W3h = (unsigned short*)(ws + 20989952);
  unsigned short* W3l = (unsigned short*)(ws + 21026816);
  unsigned short* WTh = (unsigned short*)(ws + 21063680);
  unsigned short* WTl = (unsigned short*)(ws + 21069824);
  float* c3   = ws;
  float* node = ws + 4194304;
  float* gx   = ws + 6291456;
  unsigned short* Abf  = (unsigned short*)(ws + 8388608);
  unsigned short* A2bf = (unsigned short*)(ws + 9437184);
  float* mo   = ws + 10485760;
  float* out  = (float*)d_out;

  wprep_k <<<408, 256, 0, stream>>>(Wc2, Wc3, Wh, W2h, W2l, W3h, W3l, WTh, WTl);
  conv1_k <<<512, 256, 0, stream>>>(frames, Wc1, bc1, c1h, c1l);
  conv2m_k<<<512, 256, 0, stream>>>(c1h, c1l, W2h, W2l, bc2, c2h);
  conv3m_k<<<512, 256, 0, stream>>>(c2h, W3h, W3l, bc3, c3);
  embed_k <<<512, 256, 0, stream>>>(c3, We, be, node);
  prep_k  <<<512, 256, 0, stream>>>(adj, node, Wx, Abf, A2bf, gx);
  seq2_k  <<<8,  1024, 0, stream>>>(Abf, A2bf, gx, h0, WTh, WTl, bg, tau, Ap, mo, out);
  dec_k   <<<512, 128, 0, stream>>>(mo, Wd1, bd1, Wd2, bd2, Wd3, bd3, out);
}

// Round 8
// 320.156 us; speedup vs baseline: 2.9438x; 1.0536x over previous
//
#include <hip/hip_runtime.h>
#include <hip/hip_bf16.h>

#define SH 68            // padded LDS row stride (floats) for fp32 prep kernels
#define DT_C 0.1f

typedef short bfrag __attribute__((ext_vector_type(8)));     // 8 bf16
typedef _Float16 hfrag __attribute__((ext_vector_type(8)));  // 8 fp16
typedef float f32x4 __attribute__((ext_vector_type(4)));

union FU { bfrag v; unsigned short s[8]; uint4 q; };
union HU { hfrag v; unsigned short s[8]; uint4 q; };

__device__ __forceinline__ unsigned short bf16_rn(float x) {
  union { float f; unsigned u; } v; v.f = x;
  unsigned r = v.u + 0x7fffu + ((v.u >> 16) & 1u);
  return (unsigned short)(r >> 16);
}
__device__ __forceinline__ float bf16_tof(unsigned short h) {
  union { unsigned u; float f; } v; v.u = ((unsigned)h) << 16; return v.f;
}
// native RNE f32->bf16 (compiler fuses pairs into v_cvt_pk_bf16_f32)
__device__ __forceinline__ unsigned short bfu(float x) {
  union { __hip_bfloat16 b; unsigned short u; } cv;
  cv.b = __float2bfloat16(x);
  return cv.u;
}
__device__ __forceinline__ float tanh_f(float x) {
  return 1.0f - 2.0f / (__expf(2.0f * x) + 1.0f);
}
// fp16 hi/lo split of a float
__device__ __forceinline__ void h16split(float v, unsigned short& hu, unsigned short& lu) {
  union { _Float16 h; unsigned short u; } a, b;
  a.h = (_Float16)v;
  b.h = (_Float16)(v - (float)a.h);
  hu = a.u; lu = b.u;
}
__device__ __forceinline__ unsigned short h16hi(float v) {
  union { _Float16 h; unsigned short u; } a; a.h = (_Float16)v; return a.u;
}

// ---- fp32 4x4-block 64-K matmul helper, float4 A-reads (A stride SH) ----
// acc += A[n0..n0+3][*] * B[*][e0..e0+3]; B stride sb (LDS or global)
__device__ __forceinline__ void mm16(const float* __restrict__ A,
                                     const float* __restrict__ B, int sb,
                                     float acc[4][4], int n0, int e0) {
  #pragma unroll 4
  for (int k4 = 0; k4 < 16; ++k4) {
    float4 av0 = *(const float4*)(A + (n0+0)*SH + k4*4);
    float4 av1 = *(const float4*)(A + (n0+1)*SH + k4*4);
    float4 av2 = *(const float4*)(A + (n0+2)*SH + k4*4);
    float4 av3 = *(const float4*)(A + (n0+3)*SH + k4*4);
    const float a0j[4] = {av0.x, av0.y, av0.z, av0.w};
    const float a1j[4] = {av1.x, av1.y, av1.z, av1.w};
    const float a2j[4] = {av2.x, av2.y, av2.z, av2.w};
    const float a3j[4] = {av3.x, av3.y, av3.z, av3.w};
    #pragma unroll
    for (int j = 0; j < 4; ++j) {
      const float4 bv = *(const float4*)(B + (k4*4+j)*sb + e0);
      acc[0][0]+=a0j[j]*bv.x; acc[0][1]+=a0j[j]*bv.y; acc[0][2]+=a0j[j]*bv.z; acc[0][3]+=a0j[j]*bv.w;
      acc[1][0]+=a1j[j]*bv.x; acc[1][1]+=a1j[j]*bv.y; acc[1][2]+=a1j[j]*bv.z; acc[1][3]+=a1j[j]*bv.w;
      acc[2][0]+=a2j[j]*bv.x; acc[2][1]+=a2j[j]*bv.y; acc[2][2]+=a2j[j]*bv.z; acc[2][3]+=a2j[j]*bv.w;
      acc[3][0]+=a3j[j]*bv.x; acc[3][1]+=a3j[j]*bv.y; acc[3][2]+=a3j[j]*bv.z; acc[3][3]+=a3j[j]*bv.w;
    }
  }
}

// ---- fused weight prep ----
__global__ __launch_bounds__(256) void wprep_k(const float* __restrict__ Wc2,
                                               const float* __restrict__ Wc3,
                                               const float* __restrict__ Wh,
                                               unsigned short* __restrict__ W2h,
                                               unsigned short* __restrict__ W2l,
                                               unsigned short* __restrict__ W3h,
                                               unsigned short* __restrict__ W3l,
                                               unsigned short* __restrict__ WTh,
                                               unsigned short* __restrict__ WTl) {
  int i = blockIdx.x * 256 + threadIdx.x;
  if (i < 18432) {
    int oc = i / 288, rem = i % 288, pos = rem >> 5, ic = rem & 31;
    float v = Wc2[oc*288 + ic*9 + pos];
    h16split(v, W2h[i], W2l[i]);
  } else if (i < 18432 + 73728) {
    int j = i - 18432;
    int oc = j / 576, rem = j % 576, pos = rem >> 6, ic = rem & 63;
    float v = Wc3[oc*576 + ic*9 + pos];
    h16split(v, W3h[j], W3l[j]);
  } else if (i < 18432 + 73728 + 12288) {
    int j = i - 92160;
    int k3 = j >> 12, rem = j & 4095, din = rem >> 6, dout = rem & 63;
    float v = Wh[j];
    unsigned short hi = bf16_rn(v);
    WTh[k3*4096 + dout*64 + din] = hi;
    WTl[k3*4096 + dout*64 + din] = bf16_rn(v - bf16_tof(hi));
  }
}

// ---- conv1: [512,3,64,64] -> fp16 hi plane in conv2-staging layout ----
__global__ __launch_bounds__(256) void conv1_k(const float* __restrict__ frames,
                                               const float* __restrict__ W,
                                               const float* __restrict__ bias,
                                               unsigned short* __restrict__ c1h) {
  __shared__ __align__(16) float sIn[12288];
  int bt = blockIdx.x, tid = threadIdx.x;
  const float4* src = (const float4*)(frames + (size_t)bt * 12288);
  for (int i = tid; i < 3072; i += 256) ((float4*)sIn)[i] = src[i];
  __syncthreads();
  for (int p = tid; p < 1024; p += 256) {
    int ho = p >> 5, wo = p & 31, hi0 = ho*2-1, wi0 = wo*2-1;
    int obase = (((ho*2 + (wo&1))*16 + (wo>>1)))*8;
    for (int ocb = 0; ocb < 4; ++ocb) {
      float acc[8];
      #pragma unroll
      for (int j = 0; j < 8; ++j) acc[j] = bias[ocb*8+j];
      for (int ic = 0; ic < 3; ++ic) {
        float win[9];
        #pragma unroll
        for (int kh = 0; kh < 3; ++kh) {
          int hi = hi0 + kh;
          #pragma unroll
          for (int kw = 0; kw < 3; ++kw) {
            int wi = wi0 + kw;
            win[kh*3+kw] = (hi>=0 && hi<64 && wi>=0 && wi<64) ? sIn[ic*4096 + hi*64 + wi] : 0.f;
          }
        }
        #pragma unroll
        for (int j = 0; j < 8; ++j) {
          const float* wp = W + (size_t)(ocb*8+j)*27 + ic*9;
          #pragma unroll
          for (int k = 0; k < 9; ++k) acc[j] += win[k] * wp[k];
        }
      }
      ushort hh[8];
      #pragma unroll
      for (int j = 0; j < 8; ++j) hh[j] = h16hi(fmaxf(acc[j], 0.f));
      *(uint4*)&c1h[(size_t)bt*32768 + ocb*8192 + obase] = *(uint4*)hh;
    }
  }
}

#define MFMAH(a, bb, cc) __builtin_amdgcn_mfma_f32_16x16x32_f16((a), (bb), (cc), 0, 0, 0)

// ---- conv2 implicit-GEMM MFMA: M=256 pix, N=64 oc, K=288; A fp16-hi, W hi/lo ----
__global__ __launch_bounds__(256) void conv2m_k(const unsigned short* __restrict__ c1h,
                                                const unsigned short* __restrict__ W2h,
                                                const unsigned short* __restrict__ W2l,
                                                const float* __restrict__ bias,
                                                unsigned short* __restrict__ c2h) {
  __shared__ __align__(16) unsigned short sH[32768];
  int bt = blockIdx.x, tid = threadIdx.x;
  {
    const uint4* gh = (const uint4*)(c1h + (size_t)bt*32768);
    for (int i = tid; i < 4096; i += 256) ((uint4*)sH)[i] = gh[i];
  }
  __syncthreads();
  int lane = tid & 63, w = tid >> 6, g = lane >> 4, c = lane & 15;
  f32x4 acc[4][4] = {};
  const uint4 z4 = make_uint4(0,0,0,0);
  #pragma unroll
  for (int pos = 0; pos < 9; ++pos) {
    const int kh = pos / 3, kw = pos % 3;
    HU Ah[4];
    #pragma unroll
    for (int m = 0; m < 4; ++m) {
      int pix = w*64 + m*16 + c;
      int ho = pix >> 4, wo = pix & 15;
      int hi = 2*ho - 1 + kh, wi = 2*wo - 1 + kw;
      bool ok = (hi >= 0) & (wi >= 0);
      int hic = ok ? hi : 0, wic = ok ? wi : 0;
      int a = (((g*32 + hic)*2 + (wic & 1))*16 + (wic >> 1))*8;
      uint4 vh = *(const uint4*)&sH[a];
      Ah[m].q = ok ? vh : z4;
    }
    HU Bh[4], Bl[4];
    #pragma unroll
    for (int n = 0; n < 4; ++n) {
      int off = (n*16 + c)*288 + pos*32 + g*8;
      Bh[n].q = *(const uint4*)(W2h + off);
      Bl[n].q = *(const uint4*)(W2l + off);
    }
    #pragma unroll
    for (int m = 0; m < 4; ++m)
      #pragma unroll
      for (int n = 0; n < 4; ++n) {
        acc[m][n] = MFMAH(Ah[m].v, Bh[n].v, acc[m][n]);
        acc[m][n] = MFMAH(Ah[m].v, Bl[n].v, acc[m][n]);
      }
  }
  #pragma unroll
  for (int n = 0; n < 4; ++n) {
    int oc = n*16 + c;
    float bv = bias[oc];
    int ks3 = oc >> 3, il = oc & 7;
    #pragma unroll
    for (int m = 0; m < 4; ++m) {
      #pragma unroll
      for (int r = 0; r < 4; ++r) {
        int pix = w*64 + m*16 + 4*g + r;
        int ho = pix >> 4, wo = pix & 15;
        float v = fmaxf(acc[m][n][r] + bv, 0.f);
        size_t dst = (size_t)bt*16384 + ((((ks3*16 + ho)*2 + (wo&1))*8 + (wo>>1)))*8 + il;
        c2h[dst] = h16hi(v);
      }
    }
  }
}

// ---- conv3 implicit-GEMM MFMA: M=64 pix, N=128 oc, K=576 -> fp32 c3 ----
__global__ __launch_bounds__(256) void conv3m_k(const unsigned short* __restrict__ c2h,
                                                const unsigned short* __restrict__ W3h,
                                                const unsigned short* __restrict__ W3l,
                                                const float* __restrict__ bias,
                                                float* __restrict__ c3) {
  __shared__ __align__(16) unsigned short sH[16384];
  int bt = blockIdx.x, tid = threadIdx.x;
  {
    const uint4* gh = (const uint4*)(c2h + (size_t)bt*16384);
    for (int i = tid; i < 2048; i += 256) ((uint4*)sH)[i] = gh[i];
  }
  __syncthreads();
  int lane = tid & 63, w = tid >> 6, g = lane >> 4, c = lane & 15;
  f32x4 acc[8] = {};
  const uint4 z4 = make_uint4(0,0,0,0);
  int pix = w*16 + c;
  int ho = pix >> 3, wo = pix & 7;
  #pragma unroll
  for (int pos = 0; pos < 9; ++pos) {
    const int kh = pos / 3, kw = pos % 3;
    int hi = 2*ho - 1 + kh, wi = 2*wo - 1 + kw;
    bool ok = (hi >= 0) & (wi >= 0);
    int hic = ok ? hi : 0, wic = ok ? wi : 0;
    #pragma unroll
    for (int ih = 0; ih < 2; ++ih) {
      int icg = ih*4 + g;
      int a = ((((icg*16 + hic)*2 + (wic & 1))*8 + (wic >> 1)))*8;
      HU Ah;
      uint4 vh = *(const uint4*)&sH[a];
      Ah.q = ok ? vh : z4;
      #pragma unroll
      for (int n = 0; n < 8; ++n) {
        int off = (n*16 + c)*576 + pos*64 + ih*32 + g*8;
        HU Bh, Bl;
        Bh.q = *(const uint4*)(W3h + off);
        Bl.q = *(const uint4*)(W3l + off);
        acc[n] = MFMAH(Ah.v, Bh.v, acc[n]);
        acc[n] = MFMAH(Ah.v, Bl.v, acc[n]);
      }
    }
  }
  #pragma unroll
  for (int n = 0; n < 8; ++n) {
    int oc = n*16 + c;
    float bv = bias[oc];
    #pragma unroll
    for (int r = 0; r < 4; ++r) {
      int po = w*16 + 4*g + r;
      c3[(size_t)(bt*128 + oc)*64 + po] = fmaxf(acc[n][r] + bv, 0.f);
    }
  }
}

// ---- embed: node[bt,n,e] = sum_c c3[bt,c,n] * We[c,e] + be[e] ----
__global__ __launch_bounds__(256) void embed_k(const float* __restrict__ c3,
                                               const float* __restrict__ We,
                                               const float* __restrict__ be,
                                               float* __restrict__ node) {
  __shared__ float sF[64*133];
  __shared__ __align__(16) float sWe[8192];
  int bt = blockIdx.x, tid = threadIdx.x;
  const float* src = c3 + (size_t)bt * 8192;
  for (int i = tid; i < 8192; i += 256) sF[(i & 63)*133 + (i >> 6)] = src[i];
  const float4* w4 = (const float4*)We;
  for (int i = tid; i < 2048; i += 256) ((float4*)sWe)[i] = w4[i];
  __syncthreads();
  int lane = tid & 63, w = tid >> 6, nsub = lane >> 4, eb = lane & 15;
  int n0 = w*16 + nsub*4, e0 = eb*4;
  float acc[4][4];
  #pragma unroll
  for (int jj = 0; jj < 4; ++jj)
    #pragma unroll
    for (int ee = 0; ee < 4; ++ee) acc[jj][ee] = be[e0+ee];
  for (int c = 0; c < 128; ++c) {
    float a0 = sF[(n0+0)*133+c];
    float a1 = sF[(n0+1)*133+c];
    float a2 = sF[(n0+2)*133+c];
    float a3 = sF[(n0+3)*133+c];
    const float4 bv = *(const float4*)&sWe[c*64 + e0];
    acc[0][0]+=a0*bv.x; acc[0][1]+=a0*bv.y; acc[0][2]+=a0*bv.z; acc[0][3]+=a0*bv.w;
    acc[1][0]+=a1*bv.x; acc[1][1]+=a1*bv.y; acc[1][2]+=a1*bv.z; acc[1][3]+=a1*bv.w;
    acc[2][0]+=a2*bv.x; acc[2][1]+=a2*bv.y; acc[2][2]+=a2*bv.z; acc[2][3]+=a2*bv.w;
    acc[3][0]+=a3*bv.x; acc[3][1]+=a3*bv.y; acc[3][2]+=a3*bv.z; acc[3][3]+=a3*bv.w;
  }
  float4* nd = (float4*)(node + (size_t)bt * 4096);
  #pragma unroll
  for (int jj = 0; jj < 4; ++jj)
    nd[(n0+jj)*16 + eb] = make_float4(acc[jj][0], acc[jj][1], acc[jj][2], acc[jj][3]);
}

// ---- prep: A2=A@A ; gx = x@Wx0 + A@(x@Wx1) + A2@(x@Wx2); Wx read from global (L2) ----
__global__ __launch_bounds__(256) void prep_k(const float* __restrict__ adj,
                                              const float* __restrict__ node,
                                              const float* __restrict__ Wx,
                                              unsigned short* __restrict__ Abf,
                                              unsigned short* __restrict__ A2bf,
                                              float* __restrict__ gxg) {
  __shared__ __align__(16) float sA[64*SH], sA2[64*SH], sN[64*SH], sZ[64*SH];
  int bt = blockIdx.x, tid = threadIdx.x;
  {
    const float4* a4 = (const float4*)(adj + (size_t)bt * 4096);
    const float4* n4 = (const float4*)(node + (size_t)bt * 4096);
    for (int i = tid; i < 1024; i += 256) {
      int r = i >> 4, c = (i & 15) * 4;
      *(float4*)&sA[r*SH+c] = a4[i];
      *(float4*)&sN[r*SH+c] = n4[i];
    }
  }
  __syncthreads();
  int lane = tid & 63, w = tid >> 6, nsub = lane >> 4, eb = lane & 15;
  int n0 = w*16 + nsub*4, e0 = eb*4;
  float4* gxout = (float4*)(gxg + (size_t)bt * 4096);
  for (int i = tid; i < 1024; i += 256) {
    int r = i >> 4, c0 = (i & 15) * 4;
    ushort4 o;
    o.x = bf16_rn(sA[r*SH+c0+0]); o.y = bf16_rn(sA[r*SH+c0+1]);
    o.z = bf16_rn(sA[r*SH+c0+2]); o.w = bf16_rn(sA[r*SH+c0+3]);
    *(ushort4*)&Abf[(size_t)bt*4096 + r*64 + c0] = o;
  }
  {
    float a2t[4][4] = {};
    mm16(sA, sA, SH, a2t, n0, e0);
    #pragma unroll
    for (int jj = 0; jj < 4; ++jj) {
      *(float4*)&sA2[(n0+jj)*SH+e0] = make_float4(a2t[jj][0], a2t[jj][1], a2t[jj][2], a2t[jj][3]);
      ushort4 o;
      o.x = bf16_rn(a2t[jj][0]); o.y = bf16_rn(a2t[jj][1]);
      o.z = bf16_rn(a2t[jj][2]); o.w = bf16_rn(a2t[jj][3]);
      *(ushort4*)&A2bf[(size_t)bt*4096 + (n0+jj)*64 + e0] = o;
    }
  }
  {
    float t[4][4] = {};
    mm16(sN, Wx + 4096, 64, t, n0, e0);        // z1 = x @ Wx1 (global B)
    #pragma unroll
    for (int jj = 0; jj < 4; ++jj)
      *(float4*)&sZ[(n0+jj)*SH+e0] = make_float4(t[jj][0], t[jj][1], t[jj][2], t[jj][3]);
  }
  __syncthreads();
  float gx[4][4] = {};
  mm16(sA, sZ, SH, gx, n0, e0);                // gx = A @ z1
  __syncthreads();
  {
    float t[4][4] = {};
    mm16(sN, Wx + 8192, 64, t, n0, e0);        // z2 = x @ Wx2 (global B)
    #pragma unroll
    for (int jj = 0; jj < 4; ++jj)
      *(float4*)&sZ[(n0+jj)*SH+e0] = make_float4(t[jj][0], t[jj][1], t[jj][2], t[jj][3]);
  }
  __syncthreads();
  mm16(sA2, sZ, SH, gx, n0, e0);               // gx += A2 @ z2
  mm16(sN, Wx, 64, gx, n0, e0);                // gx += x @ Wx0 (global B)
  #pragma unroll
  for (int jj = 0; jj < 4; ++jj)
    gxout[(n0+jj)*16 + eb] = make_float4(gx[jj][0], gx[jj][1], gx[jj][2], gx[jj][3]);
}

#define MFMA(a, bb, cc) __builtin_amdgcn_mfma_f32_16x16x32_bf16((a), (bb), (cc), 0, 0, 0)

// ---- sequential recurrence via MFMA: one block per batch chain, 16 waves ----
__global__ __launch_bounds__(1024, 4) void seq2_k(
    const unsigned short* __restrict__ Abf, const unsigned short* __restrict__ A2bf,
    const float* __restrict__ gxg, const float* __restrict__ h0,
    const unsigned short* __restrict__ WTh, const unsigned short* __restrict__ WTl,
    const float* __restrict__ bg, const float* __restrict__ tau, const float* __restrict__ Apv,
    float* __restrict__ mout, float* __restrict__ out) {
  __shared__ unsigned short sHh[64*72];
  __shared__ unsigned short sA[2][64*72], sA2[2][64*72];
  __shared__ unsigned short sZ1[64*72], sZ2[64*72];
  __shared__ float sPart[64*17];
  int b = blockIdx.x, tid = threadIdx.x;
  int lane = tid & 63, w = tid >> 6, g = lane >> 4, c = lane & 15;
  int mt = w & 3, nt = w >> 2;
  int e = nt*16 + c;
  int mrow = mt*16 + 4*g;
  float itau = 1.f/tau[e], apv = Apv[e], bgv = bg[e];
  FU wf[3][2][2];                          // [k3][kt][hi/lo]
  #pragma unroll
  for (int k3 = 0; k3 < 3; ++k3)
    #pragma unroll
    for (int kt = 0; kt < 2; ++kt) {
      int off = k3*4096 + e*64 + kt*32 + 8*g;
      wf[k3][kt][0].q = *(const uint4*)(WTh + off);
      wf[k3][kt][1].q = *(const uint4*)(WTl + off);
    }
  float hm[4];
  #pragma unroll
  for (int r = 0; r < 4; ++r) hm[r] = h0[(size_t)b*4096 + (mrow+r)*64 + e];
  #pragma unroll
  for (int r = 0; r < 4; ++r) sHh[(mrow+r)*72 + e] = bfu(hm[r]);
  {  // stage t=0 A/A2
    int row = tid >> 4, k0 = (tid & 15) * 4;
    *(uint2*)&sA[0][row*72 + k0]  = *(const uint2*)(Abf  + (size_t)b*64*4096 + tid*4);
    *(uint2*)&sA2[0][row*72 + k0] = *(const uint2*)(A2bf + (size_t)b*64*4096 + tid*4);
  }
  __syncthreads();
  #pragma unroll 1
  for (int t = 0; t < 64; ++t) {
    int cur = t & 1;
    size_t bt = (size_t)b*64 + t;
    int tn = (t < 63) ? t + 1 : t;
    uint2 pa  = *(const uint2*)(Abf  + ((size_t)b*64 + tn)*4096 + tid*4);
    uint2 pa2 = *(const uint2*)(A2bf + ((size_t)b*64 + tn)*4096 + tid*4);
    float gxv[4];
    {
      const float* gp = gxg + bt*4096;
      #pragma unroll
      for (int r = 0; r < 4; ++r) gxv[r] = gp[(mrow+r)*64 + e];
    }
    // ---- z-phase: z1 = h@Wh1, z2 = h@Wh2 (split chains per kt) ----
    FU ha[2];
    #pragma unroll
    for (int kt = 0; kt < 2; ++kt)
      ha[kt].q = *(const uint4*)&sHh[(mt*16 + c)*72 + kt*32 + 8*g];
    f32x4 a1a = {0.f,0.f,0.f,0.f}, a1b = {0.f,0.f,0.f,0.f};
    f32x4 a2a = {0.f,0.f,0.f,0.f}, a2b = {0.f,0.f,0.f,0.f};
    a1a = MFMA(ha[0].v, wf[1][0][0].v, a1a);
    a1a = MFMA(ha[0].v, wf[1][0][1].v, a1a);
    a1b = MFMA(ha[1].v, wf[1][1][0].v, a1b);
    a1b = MFMA(ha[1].v, wf[1][1][1].v, a1b);
    a2a = MFMA(ha[0].v, wf[2][0][0].v, a2a);
    a2a = MFMA(ha[0].v, wf[2][0][1].v, a2a);
    a2b = MFMA(ha[1].v, wf[2][1][0].v, a2b);
    a2b = MFMA(ha[1].v, wf[2][1][1].v, a2b);
    f32x4 a1 = a1a + a1b, a2 = a2a + a2b;
    {
      ushort4 o1, o2;
      o1.x = bfu(a1[0]); o1.y = bfu(a1[1]); o1.z = bfu(a1[2]); o1.w = bfu(a1[3]);
      o2.x = bfu(a2[0]); o2.y = bfu(a2[1]); o2.z = bfu(a2[2]); o2.w = bfu(a2[3]);
      *(ushort4*)&sZ1[e*72 + mrow] = o1;
      *(ushort4*)&sZ2[e*72 + mrow] = o2;
    }
    __syncthreads();   // B1
    // ---- gc-phase: gc = h@Wh0 + A@z1 + A2@z2 (split chains per kt) ----
    f32x4 acc0 = {0.f,0.f,0.f,0.f}, acc1 = {0.f,0.f,0.f,0.f};
    #pragma unroll
    for (int kt = 0; kt < 2; ++kt) {
      FU aA, aA2, z1f, z2f;
      int ao = (mt*16 + c)*72 + kt*32 + 8*g;
      aA.q  = *(const uint4*)&sA[cur][ao];
      aA2.q = *(const uint4*)&sA2[cur][ao];
      z1f.q = *(const uint4*)&sZ1[e*72 + kt*32 + 8*g];
      z2f.q = *(const uint4*)&sZ2[e*72 + kt*32 + 8*g];
      f32x4& acc = kt ? acc1 : acc0;
      acc = MFMA(ha[kt].v, wf[0][kt][0].v, acc);
      acc = MFMA(ha[kt].v, wf[0][kt][1].v, acc);
      acc = MFMA(aA.v,  z1f.v, acc);
      acc = MFMA(aA2.v, z2f.v, acc);
    }
    f32x4 acc = acc0 + acc1;
    // h update + write-back + mean partials
    float ps = 0.f;
    #pragma unroll
    for (int r = 0; r < 4; ++r) {
      float gc = acc[r] + gxv[r] + bgv;
      float f = tanh_f(gc);
      float hn = hm[r] + DT_C * (-(itau + f) * hm[r] + f * apv);
      hm[r] = hn;
      ps += hn;
      sHh[(mrow+r)*72 + e] = bfu(hn);
    }
    sPart[e*17 + mt*4 + g] = ps;
    {  // staging write for next step
      int row = tid >> 4, k0 = (tid & 15) * 4;
      *(uint2*)&sA[cur^1][row*72 + k0]  = pa;
      *(uint2*)&sA2[cur^1][row*72 + k0] = pa2;
    }
    __syncthreads();   // B2
    if (lane < 4) {
      int ee = w*4 + lane;
      float s = 0.f;
      #pragma unroll
      for (int j = 0; j < 16; ++j) s += sPart[ee*17 + j];
      mout[bt*64 + ee] = s * (1.0f / 64.0f);
    }
  }
  #pragma unroll
  for (int r = 0; r < 4; ++r)
    out[512 + (size_t)b*4096 + (mrow+r)*64 + e] = hm[r];
}

// ---- decoder MLP for all (b,t) in parallel ----
__global__ __launch_bounds__(128) void dec_k(const float* __restrict__ mout,
                                             const float* __restrict__ Wd1, const float* __restrict__ bd1,
                                             const float* __restrict__ Wd2, const float* __restrict__ bd2,
                                             const float* __restrict__ Wd3, const float* __restrict__ bd3,
                                             float* __restrict__ out) {
  __shared__ float sm[64], sd1[128], sd2[64];
  int bt = blockIdx.x, tid = threadIdx.x;
  if (tid < 64) sm[tid] = mout[(size_t)bt*64 + tid];
  __syncthreads();
  {
    float a = bd1[tid];
    #pragma unroll 8
    for (int e = 0; e < 64; ++e) a += sm[e] * Wd1[e*128 + tid];
    sd1[tid] = fmaxf(a, 0.f);
  }
  __syncthreads();
  if (tid < 64) {
    float a = bd2[tid];
    #pragma unroll 8
    for (int i = 0; i < 128; ++i) a += sd1[i] * Wd2[i*64 + tid];
    sd2[tid] = fmaxf(a, 0.f);
  }
  __syncthreads();
  if (tid < 64) {
    float p = sd2[tid] * Wd3[tid];
    #pragma unroll
    for (int off = 32; off > 0; off >>= 1) p += __shfl_down(p, off, 64);
    if (tid == 0) out[bt] = p + bd3[0];
  }
}

extern "C" void kernel_launch(void* const* d_in, const int* in_sizes, int n_in,
                              void* d_out, int out_size, void* d_ws, size_t ws_size,
                              hipStream_t stream) {
  const float* frames = (const float*)d_in[0];
  const float* adj    = (const float*)d_in[1];
  const float* h0     = (const float*)d_in[2];
  const float* Wc1 = (const float*)d_in[3];  const float* bc1 = (const float*)d_in[4];
  const float* Wc2 = (const float*)d_in[5];  const float* bc2 = (const float*)d_in[6];
  const float* Wc3 = (const float*)d_in[7];  const float* bc3 = (const float*)d_in[8];
  const float* We  = (const float*)d_in[9];  const float* be  = (const float*)d_in[10];
  const float* Wh  = (const float*)d_in[11]; const float* Wx  = (const float*)d_in[12];
  const float* bg  = (const float*)d_in[13]; const float* tau = (const float*)d_in[14];
  const float* Ap  = (const float*)d_in[15];
  const float* Wd1 = (const float*)d_in[16]; const float* bd1 = (const float*)d_in[17];
  const float* Wd2 = (const float*)d_in[18]; const float* bd2 = (const float*)d_in[19];
  const float* Wd3 = (const float*)d_in[20]; const float* bd3 = (const float*)d_in[21];

  float* ws = (float*)d_ws;
  // Workspace map (float offsets; 25,165,824-float budget) — validated R5-R7.
  unsigned short* c1h = (unsigned short*)(ws);
  unsigned short* c2h = (unsigned short*)(ws + 16777216);
  unsigned short* W2h = (unsigned short*)(ws + 20971520);
  unsigned short* W2l = (unsigned short*)(ws + 20980736);
  unsigned short* W3h = (unsigned short*)(ws + 20989952);
  unsigned short* W3l = (unsigned short*)(ws + 21026816);
  unsigned short* WTh = (unsigned short*)(ws + 21063680);
  unsigned short* WTl = (unsigned short*)(ws + 21069824);
  float* c3   = ws;                              // reuse c1h (dead after conv2m)
  float* node = ws + 4194304;
  float* gx   = ws + 6291456;
  unsigned short* Abf  = (unsigned short*)(ws + 8388608);
  unsigned short* A2bf = (unsigned short*)(ws + 9437184);
  float* mo   = ws + 10485760;
  float* out  = (float*)d_out;

  wprep_k <<<408, 256, 0, stream>>>(Wc2, Wc3, Wh, W2h, W2l, W3h, W3l, WTh, WTl);
  conv1_k <<<512, 256, 0, stream>>>(frames, Wc1, bc1, c1h);
  conv2m_k<<<512, 256, 0, stream>>>(c1h, W2h, W2l, bc2, c2h);
  conv3m_k<<<512, 256, 0, stream>>>(c2h, W3h, W3l, bc3, c3);
  embed_k <<<512, 256, 0, stream>>>(c3, We, be, node);
  prep_k  <<<512, 256, 0, stream>>>(adj, node, Wx, Abf, A2bf, gx);
  seq2_k  <<<8,  1024, 0, stream>>>(Abf, A2bf, gx, h0, WTh, WTl, bg, tau, Ap, mo, out);
  dec_k   <<<512, 128, 0, stream>>>(mo, Wd1, bd1, Wd2, bd2, Wd3, bd3, out);
}

// Round 9
// 302.236 us; speedup vs baseline: 3.1183x; 1.0593x over previous
//
#include <hip/hip_runtime.h>
#include <hip/hip_bf16.h>

#define SH 68            // padded LDS row stride (floats) for fp32 prep kernels
#define DT_C 0.1f

typedef short bfrag __attribute__((ext_vector_type(8)));     // 8 bf16
typedef _Float16 hfrag __attribute__((ext_vector_type(8)));  // 8 fp16
typedef float f32x4 __attribute__((ext_vector_type(4)));

union FU { bfrag v; unsigned short s[8]; uint4 q; };
union HU { hfrag v; unsigned short s[8]; uint4 q; };

__device__ __forceinline__ unsigned short bf16_rn(float x) {
  union { float f; unsigned u; } v; v.f = x;
  unsigned r = v.u + 0x7fffu + ((v.u >> 16) & 1u);
  return (unsigned short)(r >> 16);
}
__device__ __forceinline__ float bf16_tof(unsigned short h) {
  union { unsigned u; float f; } v; v.u = ((unsigned)h) << 16; return v.f;
}
// native RNE f32->bf16 (compiler fuses pairs into v_cvt_pk_bf16_f32)
__device__ __forceinline__ unsigned short bfu(float x) {
  union { __hip_bfloat16 b; unsigned short u; } cv;
  cv.b = __float2bfloat16(x);
  return cv.u;
}
__device__ __forceinline__ float tanh_f(float x) {
  return 1.0f - 2.0f / (__expf(2.0f * x) + 1.0f);
}
// fp16 hi/lo split of a float
__device__ __forceinline__ void h16split(float v, unsigned short& hu, unsigned short& lu) {
  union { _Float16 h; unsigned short u; } a, b;
  a.h = (_Float16)v;
  b.h = (_Float16)(v - (float)a.h);
  hu = a.u; lu = b.u;
}
__device__ __forceinline__ unsigned short h16hi(float v) {
  union { _Float16 h; unsigned short u; } a; a.h = (_Float16)v; return a.u;
}

// ---- fp32 4x4-block 64-K matmul helper, float4 A-reads (A stride SH) ----
__device__ __forceinline__ void mm16(const float* __restrict__ A,
                                     const float* __restrict__ B, int sb,
                                     float acc[4][4], int n0, int e0) {
  #pragma unroll 4
  for (int k4 = 0; k4 < 16; ++k4) {
    float4 av0 = *(const float4*)(A + (n0+0)*SH + k4*4);
    float4 av1 = *(const float4*)(A + (n0+1)*SH + k4*4);
    float4 av2 = *(const float4*)(A + (n0+2)*SH + k4*4);
    float4 av3 = *(const float4*)(A + (n0+3)*SH + k4*4);
    const float a0j[4] = {av0.x, av0.y, av0.z, av0.w};
    const float a1j[4] = {av1.x, av1.y, av1.z, av1.w};
    const float a2j[4] = {av2.x, av2.y, av2.z, av2.w};
    const float a3j[4] = {av3.x, av3.y, av3.z, av3.w};
    #pragma unroll
    for (int j = 0; j < 4; ++j) {
      const float4 bv = *(const float4*)(B + (k4*4+j)*sb + e0);
      acc[0][0]+=a0j[j]*bv.x; acc[0][1]+=a0j[j]*bv.y; acc[0][2]+=a0j[j]*bv.z; acc[0][3]+=a0j[j]*bv.w;
      acc[1][0]+=a1j[j]*bv.x; acc[1][1]+=a1j[j]*bv.y; acc[1][2]+=a1j[j]*bv.z; acc[1][3]+=a1j[j]*bv.w;
      acc[2][0]+=a2j[j]*bv.x; acc[2][1]+=a2j[j]*bv.y; acc[2][2]+=a2j[j]*bv.z; acc[2][3]+=a2j[j]*bv.w;
      acc[3][0]+=a3j[j]*bv.x; acc[3][1]+=a3j[j]*bv.y; acc[3][2]+=a3j[j]*bv.z; acc[3][3]+=a3j[j]*bv.w;
    }
  }
}

// ---- fused weight prep: Wc2->W2 (18432), Wc3->W3 (73728), Wh->WT (12288), We->WeT (8192) ----
__global__ __launch_bounds__(256) void wprep_k(const float* __restrict__ Wc2,
                                               const float* __restrict__ Wc3,
                                               const float* __restrict__ Wh,
                                               const float* __restrict__ We,
                                               unsigned short* __restrict__ W2h,
                                               unsigned short* __restrict__ W2l,
                                               unsigned short* __restrict__ W3h,
                                               unsigned short* __restrict__ W3l,
                                               unsigned short* __restrict__ WTh,
                                               unsigned short* __restrict__ WTl,
                                               unsigned short* __restrict__ WeTh,
                                               unsigned short* __restrict__ WeTl) {
  int i = blockIdx.x * 256 + threadIdx.x;
  if (i < 18432) {
    int oc = i / 288, rem = i % 288, pos = rem >> 5, ic = rem & 31;
    float v = Wc2[oc*288 + ic*9 + pos];
    h16split(v, W2h[i], W2l[i]);
  } else if (i < 18432 + 73728) {
    int j = i - 18432;
    int oc = j / 576, rem = j % 576, pos = rem >> 6, ic = rem & 63;
    float v = Wc3[oc*576 + ic*9 + pos];
    h16split(v, W3h[j], W3l[j]);
  } else if (i < 18432 + 73728 + 12288) {
    int j = i - 92160;
    int k3 = j >> 12, rem = j & 4095, din = rem >> 6, dout = rem & 63;
    float v = Wh[j];
    unsigned short hi = bf16_rn(v);
    WTh[k3*4096 + dout*64 + din] = hi;
    WTl[k3*4096 + dout*64 + din] = bf16_rn(v - bf16_tof(hi));
  } else if (i < 18432 + 73728 + 12288 + 8192) {
    int j = i - 104448;                    // WeT[e][oc] hi/lo from We[oc][e]
    int e = j >> 7, oc = j & 127;
    float v = We[oc*64 + e];
    h16split(v, WeTh[j], WeTl[j]);
  }
}

// ---- conv1: [512,3,64,64] -> fp16 hi plane in conv2-staging layout ----
__global__ __launch_bounds__(256) void conv1_k(const float* __restrict__ frames,
                                               const float* __restrict__ W,
                                               const float* __restrict__ bias,
                                               unsigned short* __restrict__ c1h) {
  __shared__ __align__(16) float sIn[12288];
  int bt = blockIdx.x, tid = threadIdx.x;
  const float4* src = (const float4*)(frames + (size_t)bt * 12288);
  for (int i = tid; i < 3072; i += 256) ((float4*)sIn)[i] = src[i];
  __syncthreads();
  for (int p = tid; p < 1024; p += 256) {
    int ho = p >> 5, wo = p & 31, hi0 = ho*2-1, wi0 = wo*2-1;
    int obase = (((ho*2 + (wo&1))*16 + (wo>>1)))*8;
    for (int ocb = 0; ocb < 4; ++ocb) {
      float acc[8];
      #pragma unroll
      for (int j = 0; j < 8; ++j) acc[j] = bias[ocb*8+j];
      for (int ic = 0; ic < 3; ++ic) {
        float win[9];
        #pragma unroll
        for (int kh = 0; kh < 3; ++kh) {
          int hi = hi0 + kh;
          #pragma unroll
          for (int kw = 0; kw < 3; ++kw) {
            int wi = wi0 + kw;
            win[kh*3+kw] = (hi>=0 && hi<64 && wi>=0 && wi<64) ? sIn[ic*4096 + hi*64 + wi] : 0.f;
          }
        }
        #pragma unroll
        for (int j = 0; j < 8; ++j) {
          const float* wp = W + (size_t)(ocb*8+j)*27 + ic*9;
          #pragma unroll
          for (int k = 0; k < 9; ++k) acc[j] += win[k] * wp[k];
        }
      }
      ushort hh[8];
      #pragma unroll
      for (int j = 0; j < 8; ++j) hh[j] = h16hi(fmaxf(acc[j], 0.f));
      *(uint4*)&c1h[(size_t)bt*32768 + ocb*8192 + obase] = *(uint4*)hh;
    }
  }
}

#define MFMAH(a, bb, cc) __builtin_amdgcn_mfma_f32_16x16x32_f16((a), (bb), (cc), 0, 0, 0)

// ---- conv2 implicit-GEMM MFMA: M=256 pix, N=64 oc, K=288; A fp16-hi, W hi/lo ----
__global__ __launch_bounds__(256) void conv2m_k(const unsigned short* __restrict__ c1h,
                                                const unsigned short* __restrict__ W2h,
                                                const unsigned short* __restrict__ W2l,
                                                const float* __restrict__ bias,
                                                unsigned short* __restrict__ c2h) {
  __shared__ __align__(16) unsigned short sH[32768];
  int bt = blockIdx.x, tid = threadIdx.x;
  {
    const uint4* gh = (const uint4*)(c1h + (size_t)bt*32768);
    for (int i = tid; i < 4096; i += 256) ((uint4*)sH)[i] = gh[i];
  }
  __syncthreads();
  int lane = tid & 63, w = tid >> 6, g = lane >> 4, c = lane & 15;
  f32x4 acc[4][4] = {};
  const uint4 z4 = make_uint4(0,0,0,0);
  #pragma unroll
  for (int pos = 0; pos < 9; ++pos) {
    const int kh = pos / 3, kw = pos % 3;
    HU Ah[4];
    #pragma unroll
    for (int m = 0; m < 4; ++m) {
      int pix = w*64 + m*16 + c;
      int ho = pix >> 4, wo = pix & 15;
      int hi = 2*ho - 1 + kh, wi = 2*wo - 1 + kw;
      bool ok = (hi >= 0) & (wi >= 0);
      int hic = ok ? hi : 0, wic = ok ? wi : 0;
      int a = (((g*32 + hic)*2 + (wic & 1))*16 + (wic >> 1))*8;
      uint4 vh = *(const uint4*)&sH[a];
      Ah[m].q = ok ? vh : z4;
    }
    HU Bh[4], Bl[4];
    #pragma unroll
    for (int n = 0; n < 4; ++n) {
      int off = (n*16 + c)*288 + pos*32 + g*8;
      Bh[n].q = *(const uint4*)(W2h + off);
      Bl[n].q = *(const uint4*)(W2l + off);
    }
    #pragma unroll
    for (int m = 0; m < 4; ++m)
      #pragma unroll
      for (int n = 0; n < 4; ++n) {
        acc[m][n] = MFMAH(Ah[m].v, Bh[n].v, acc[m][n]);
        acc[m][n] = MFMAH(Ah[m].v, Bl[n].v, acc[m][n]);
      }
  }
  #pragma unroll
  for (int n = 0; n < 4; ++n) {
    int oc = n*16 + c;
    float bv = bias[oc];
    int ks3 = oc >> 3, il = oc & 7;
    #pragma unroll
    for (int m = 0; m < 4; ++m) {
      #pragma unroll
      for (int r = 0; r < 4; ++r) {
        int pix = w*64 + m*16 + 4*g + r;
        int ho = pix >> 4, wo = pix & 15;
        float v = fmaxf(acc[m][n][r] + bv, 0.f);
        size_t dst = (size_t)bt*16384 + ((((ks3*16 + ho)*2 + (wo&1))*8 + (wo>>1)))*8 + il;
        c2h[dst] = h16hi(v);
      }
    }
  }
}

// ---- conv3+embed fused: conv3 MFMA (M=64,N=128,K=576) -> feats fp16 LDS ->
//      embed MFMA (M=64,N=64,K=128) -> node fp32 ----
__global__ __launch_bounds__(256) void conv3e_k(const unsigned short* __restrict__ c2h,
                                                const unsigned short* __restrict__ W3h,
                                                const unsigned short* __restrict__ W3l,
                                                const float* __restrict__ bias,
                                                const unsigned short* __restrict__ WeTh,
                                                const unsigned short* __restrict__ WeTl,
                                                const float* __restrict__ be,
                                                float* __restrict__ node) {
  __shared__ __align__(16) unsigned short sH[16384];
  __shared__ __align__(16) unsigned short sF[64*136];   // feats [pix][oc] fp16, pad 136
  int bt = blockIdx.x, tid = threadIdx.x;
  {
    const uint4* gh = (const uint4*)(c2h + (size_t)bt*16384);
    for (int i = tid; i < 2048; i += 256) ((uint4*)sH)[i] = gh[i];
  }
  __syncthreads();
  int lane = tid & 63, w = tid >> 6, g = lane >> 4, c = lane & 15;
  f32x4 acc[8] = {};
  const uint4 z4 = make_uint4(0,0,0,0);
  int pix = w*16 + c;
  int ho = pix >> 3, wo = pix & 7;
  #pragma unroll
  for (int pos = 0; pos < 9; ++pos) {
    const int kh = pos / 3, kw = pos % 3;
    int hi = 2*ho - 1 + kh, wi = 2*wo - 1 + kw;
    bool ok = (hi >= 0) & (wi >= 0);
    int hic = ok ? hi : 0, wic = ok ? wi : 0;
    #pragma unroll
    for (int ih = 0; ih < 2; ++ih) {
      int icg = ih*4 + g;
      int a = ((((icg*16 + hic)*2 + (wic & 1))*8 + (wic >> 1)))*8;
      HU Ah;
      uint4 vh = *(const uint4*)&sH[a];
      Ah.q = ok ? vh : z4;
      #pragma unroll
      for (int n = 0; n < 8; ++n) {
        int off = (n*16 + c)*576 + pos*64 + ih*32 + g*8;
        HU Bh, Bl;
        Bh.q = *(const uint4*)(W3h + off);
        Bl.q = *(const uint4*)(W3l + off);
        acc[n] = MFMAH(Ah.v, Bh.v, acc[n]);
        acc[n] = MFMAH(Ah.v, Bl.v, acc[n]);
      }
    }
  }
  // feats (bias+relu, fp16) -> LDS [pix][oc]
  #pragma unroll
  for (int n = 0; n < 8; ++n) {
    int oc = n*16 + c;
    float bv = bias[oc];
    #pragma unroll
    for (int r = 0; r < 4; ++r) {
      int po = w*16 + 4*g + r;
      sF[po*136 + oc] = h16hi(fmaxf(acc[n][r] + bv, 0.f));
    }
  }
  __syncthreads();
  // embed: node[pix][e] = feats @ We + be ; wave w owns M-tile w (16 pix)
  f32x4 eacc[4] = {{0.f,0.f,0.f,0.f},{0.f,0.f,0.f,0.f},{0.f,0.f,0.f,0.f},{0.f,0.f,0.f,0.f}};
  #pragma unroll
  for (int kt = 0; kt < 4; ++kt) {
    HU Af;
    Af.q = *(const uint4*)&sF[(w*16 + c)*136 + kt*32 + g*8];
    #pragma unroll
    for (int n = 0; n < 4; ++n) {
      int off = (n*16 + c)*128 + kt*32 + g*8;
      HU Bh, Bl;
      Bh.q = *(const uint4*)(WeTh + off);
      Bl.q = *(const uint4*)(WeTl + off);
      eacc[n] = MFMAH(Af.v, Bh.v, eacc[n]);
      eacc[n] = MFMAH(Af.v, Bl.v, eacc[n]);
    }
  }
  #pragma unroll
  for (int n = 0; n < 4; ++n) {
    int e = n*16 + c;
    float bev = be[e];
    #pragma unroll
    for (int r = 0; r < 4; ++r) {
      int po = w*16 + 4*g + r;
      node[(size_t)bt*4096 + po*64 + e] = eacc[n][r] + bev;
    }
  }
}

// ---- prep: A2=A@A ; gx = x@Wx0 + A@(x@Wx1) + A2@(x@Wx2); Wx read from global (L2) ----
__global__ __launch_bounds__(256) void prep_k(const float* __restrict__ adj,
                                              const float* __restrict__ node,
                                              const float* __restrict__ Wx,
                                              unsigned short* __restrict__ Abf,
                                              unsigned short* __restrict__ A2bf,
                                              float* __restrict__ gxg) {
  __shared__ __align__(16) float sA[64*SH], sA2[64*SH], sN[64*SH], sZ[64*SH];
  int bt = blockIdx.x, tid = threadIdx.x;
  {
    const float4* a4 = (const float4*)(adj + (size_t)bt * 4096);
    const float4* n4 = (const float4*)(node + (size_t)bt * 4096);
    for (int i = tid; i < 1024; i += 256) {
      int r = i >> 4, c = (i & 15) * 4;
      *(float4*)&sA[r*SH+c] = a4[i];
      *(float4*)&sN[r*SH+c] = n4[i];
    }
  }
  __syncthreads();
  int lane = tid & 63, w = tid >> 6, nsub = lane >> 4, eb = lane & 15;
  int n0 = w*16 + nsub*4, e0 = eb*4;
  float4* gxout = (float4*)(gxg + (size_t)bt * 4096);
  for (int i = tid; i < 1024; i += 256) {
    int r = i >> 4, c0 = (i & 15) * 4;
    ushort4 o;
    o.x = bf16_rn(sA[r*SH+c0+0]); o.y = bf16_rn(sA[r*SH+c0+1]);
    o.z = bf16_rn(sA[r*SH+c0+2]); o.w = bf16_rn(sA[r*SH+c0+3]);
    *(ushort4*)&Abf[(size_t)bt*4096 + r*64 + c0] = o;
  }
  {
    float a2t[4][4] = {};
    mm16(sA, sA, SH, a2t, n0, e0);
    #pragma unroll
    for (int jj = 0; jj < 4; ++jj) {
      *(float4*)&sA2[(n0+jj)*SH+e0] = make_float4(a2t[jj][0], a2t[jj][1], a2t[jj][2], a2t[jj][3]);
      ushort4 o;
      o.x = bf16_rn(a2t[jj][0]); o.y = bf16_rn(a2t[jj][1]);
      o.z = bf16_rn(a2t[jj][2]); o.w = bf16_rn(a2t[jj][3]);
      *(ushort4*)&A2bf[(size_t)bt*4096 + (n0+jj)*64 + e0] = o;
    }
  }
  {
    float t[4][4] = {};
    mm16(sN, Wx + 4096, 64, t, n0, e0);        // z1 = x @ Wx1
    #pragma unroll
    for (int jj = 0; jj < 4; ++jj)
      *(float4*)&sZ[(n0+jj)*SH+e0] = make_float4(t[jj][0], t[jj][1], t[jj][2], t[jj][3]);
  }
  __syncthreads();
  float gx[4][4] = {};
  mm16(sA, sZ, SH, gx, n0, e0);                // gx = A @ z1
  __syncthreads();
  {
    float t[4][4] = {};
    mm16(sN, Wx + 8192, 64, t, n0, e0);        // z2 = x @ Wx2
    #pragma unroll
    for (int jj = 0; jj < 4; ++jj)
      *(float4*)&sZ[(n0+jj)*SH+e0] = make_float4(t[jj][0], t[jj][1], t[jj][2], t[jj][3]);
  }
  __syncthreads();
  mm16(sA2, sZ, SH, gx, n0, e0);               // gx += A2 @ z2
  mm16(sN, Wx, 64, gx, n0, e0);                // gx += x @ Wx0
  #pragma unroll
  for (int jj = 0; jj < 4; ++jj)
    gxout[(n0+jj)*16 + eb] = make_float4(gx[jj][0], gx[jj][1], gx[jj][2], gx[jj][3]);
}

#define MFMA(a, bb, cc) __builtin_amdgcn_mfma_f32_16x16x32_bf16((a), (bb), (cc), 0, 0, 0)

// ---- sequential recurrence via MFMA: one block per batch chain, 16 waves ----
// (exact R7 form — the measured-best variant; R8's chain-split regressed)
__global__ __launch_bounds__(1024, 4) void seq2_k(
    const unsigned short* __restrict__ Abf, const unsigned short* __restrict__ A2bf,
    const float* __restrict__ gxg, const float* __restrict__ h0,
    const unsigned short* __restrict__ WTh, const unsigned short* __restrict__ WTl,
    const float* __restrict__ bg, const float* __restrict__ tau, const float* __restrict__ Apv,
    float* __restrict__ mout, float* __restrict__ out) {
  __shared__ unsigned short sHh[64*72];
  __shared__ unsigned short sA[2][64*72], sA2[2][64*72];
  __shared__ unsigned short sZ1[64*72], sZ2[64*72];
  __shared__ float sPart[64*17];
  int b = blockIdx.x, tid = threadIdx.x;
  int lane = tid & 63, w = tid >> 6, g = lane >> 4, c = lane & 15;
  int mt = w & 3, nt = w >> 2;
  int e = nt*16 + c;
  int mrow = mt*16 + 4*g;
  float itau = 1.f/tau[e], apv = Apv[e], bgv = bg[e];
  FU wf[3][2][2];                          // [k3][kt][hi/lo]
  #pragma unroll
  for (int k3 = 0; k3 < 3; ++k3)
    #pragma unroll
    for (int kt = 0; kt < 2; ++kt) {
      int off = k3*4096 + e*64 + kt*32 + 8*g;
      wf[k3][kt][0].q = *(const uint4*)(WTh + off);
      wf[k3][kt][1].q = *(const uint4*)(WTl + off);
    }
  float hm[4];
  #pragma unroll
  for (int r = 0; r < 4; ++r) hm[r] = h0[(size_t)b*4096 + (mrow+r)*64 + e];
  #pragma unroll
  for (int r = 0; r < 4; ++r) sHh[(mrow+r)*72 + e] = bfu(hm[r]);
  {  // stage t=0 A/A2
    int row = tid >> 4, k0 = (tid & 15) * 4;
    *(uint2*)&sA[0][row*72 + k0]  = *(const uint2*)(Abf  + (size_t)b*64*4096 + tid*4);
    *(uint2*)&sA2[0][row*72 + k0] = *(const uint2*)(A2bf + (size_t)b*64*4096 + tid*4);
  }
  __syncthreads();
  #pragma unroll 1
  for (int t = 0; t < 64; ++t) {
    int cur = t & 1;
    size_t bt = (size_t)b*64 + t;
    int tn = (t < 63) ? t + 1 : t;
    uint2 pa  = *(const uint2*)(Abf  + ((size_t)b*64 + tn)*4096 + tid*4);
    uint2 pa2 = *(const uint2*)(A2bf + ((size_t)b*64 + tn)*4096 + tid*4);
    float gxv[4];
    {
      const float* gp = gxg + bt*4096;
      #pragma unroll
      for (int r = 0; r < 4; ++r) gxv[r] = gp[(mrow+r)*64 + e];
    }
    // ---- z-phase: z1 = h@Wh1, z2 = h@Wh2 ----
    FU ha[2];
    #pragma unroll
    for (int kt = 0; kt < 2; ++kt)
      ha[kt].q = *(const uint4*)&sHh[(mt*16 + c)*72 + kt*32 + 8*g];
    f32x4 a1 = {0.f,0.f,0.f,0.f}, a2 = {0.f,0.f,0.f,0.f};
    #pragma unroll
    for (int kt = 0; kt < 2; ++kt) {
      a1 = MFMA(ha[kt].v, wf[1][kt][0].v, a1);
      a1 = MFMA(ha[kt].v, wf[1][kt][1].v, a1);
      a2 = MFMA(ha[kt].v, wf[2][kt][0].v, a2);
      a2 = MFMA(ha[kt].v, wf[2][kt][1].v, a2);
    }
    {
      ushort4 o1, o2;
      o1.x = bfu(a1[0]); o1.y = bfu(a1[1]); o1.z = bfu(a1[2]); o1.w = bfu(a1[3]);
      o2.x = bfu(a2[0]); o2.y = bfu(a2[1]); o2.z = bfu(a2[2]); o2.w = bfu(a2[3]);
      *(ushort4*)&sZ1[e*72 + mrow] = o1;
      *(ushort4*)&sZ2[e*72 + mrow] = o2;
    }
    __syncthreads();   // B1
    // ---- gc-phase: gc = h@Wh0 + A@z1 + A2@z2 + gx + bg ----
    f32x4 acc = {0.f,0.f,0.f,0.f};
    #pragma unroll
    for (int kt = 0; kt < 2; ++kt) {
      FU aA, aA2, z1f, z2f;
      int ao = (mt*16 + c)*72 + kt*32 + 8*g;
      aA.q  = *(const uint4*)&sA[cur][ao];
      aA2.q = *(const uint4*)&sA2[cur][ao];
      z1f.q = *(const uint4*)&sZ1[e*72 + kt*32 + 8*g];
      z2f.q = *(const uint4*)&sZ2[e*72 + kt*32 + 8*g];
      acc = MFMA(ha[kt].v, wf[0][kt][0].v, acc);
      acc = MFMA(ha[kt].v, wf[0][kt][1].v, acc);
      acc = MFMA(aA.v,  z1f.v, acc);
      acc = MFMA(aA2.v, z2f.v, acc);
    }
    // h update + write-back + mean partials
    float ps = 0.f;
    #pragma unroll
    for (int r = 0; r < 4; ++r) {
      float gc = acc[r] + gxv[r] + bgv;
      float f = tanh_f(gc);
      float hn = hm[r] + DT_C * (-(itau + f) * hm[r] + f * apv);
      hm[r] = hn;
      ps += hn;
      sHh[(mrow+r)*72 + e] = bfu(hn);
    }
    sPart[e*17 + mt*4 + g] = ps;
    {  // staging write for next step
      int row = tid >> 4, k0 = (tid & 15) * 4;
      *(uint2*)&sA[cur^1][row*72 + k0]  = pa;
      *(uint2*)&sA2[cur^1][row*72 + k0] = pa2;
    }
    __syncthreads();   // B2
    if (lane < 4) {
      int ee = w*4 + lane;
      float s = 0.f;
      #pragma unroll
      for (int j = 0; j < 16; ++j) s += sPart[ee*17 + j];
      mout[bt*64 + ee] = s * (1.0f / 64.0f);
    }
  }
  #pragma unroll
  for (int r = 0; r < 4; ++r)
    out[512 + (size_t)b*4096 + (mrow+r)*64 + e] = hm[r];
}

// ---- decoder MLP for all (b,t) in parallel ----
__global__ __launch_bounds__(128) void dec_k(const float* __restrict__ mout,
                                             const float* __restrict__ Wd1, const float* __restrict__ bd1,
                                             const float* __restrict__ Wd2, const float* __restrict__ bd2,
                                             const float* __restrict__ Wd3, const float* __restrict__ bd3,
                                             float* __restrict__ out) {
  __shared__ float sm[64], sd1[128], sd2[64];
  int bt = blockIdx.x, tid = threadIdx.x;
  if (tid < 64) sm[tid] = mout[(size_t)bt*64 + tid];
  __syncthreads();
  {
    float a = bd1[tid];
    #pragma unroll 8
    for (int e = 0; e < 64; ++e) a += sm[e] * Wd1[e*128 + tid];
    sd1[tid] = fmaxf(a, 0.f);
  }
  __syncthreads();
  if (tid < 64) {
    float a = bd2[tid];
    #pragma unroll 8
    for (int i = 0; i < 128; ++i) a += sd1[i] * Wd2[i*64 + tid];
    sd2[tid] = fmaxf(a, 0.f);
  }
  __syncthreads();
  if (tid < 64) {
    float p = sd2[tid] * Wd3[tid];
    #pragma unroll
    for (int off = 32; off > 0; off >>= 1) p += __shfl_down(p, off, 64);
    if (tid == 0) out[bt] = p + bd3[0];
  }
}

extern "C" void kernel_launch(void* const* d_in, const int* in_sizes, int n_in,
                              void* d_out, int out_size, void* d_ws, size_t ws_size,
                              hipStream_t stream) {
  const float* frames = (const float*)d_in[0];
  const float* adj    = (const float*)d_in[1];
  const float* h0     = (const float*)d_in[2];
  const float* Wc1 = (const float*)d_in[3];  const float* bc1 = (const float*)d_in[4];
  const float* Wc2 = (const float*)d_in[5];  const float* bc2 = (const float*)d_in[6];
  const float* Wc3 = (const float*)d_in[7];  const float* bc3 = (const float*)d_in[8];
  const float* We  = (const float*)d_in[9];  const float* be  = (const float*)d_in[10];
  const float* Wh  = (const float*)d_in[11]; const float* Wx  = (const float*)d_in[12];
  const float* bg  = (const float*)d_in[13]; const float* tau = (const float*)d_in[14];
  const float* Ap  = (const float*)d_in[15];
  const float* Wd1 = (const float*)d_in[16]; const float* bd1 = (const float*)d_in[17];
  const float* Wd2 = (const float*)d_in[18]; const float* bd2 = (const float*)d_in[19];
  const float* Wd3 = (const float*)d_in[20]; const float* bd3 = (const float*)d_in[21];

  float* ws = (float*)d_ws;
  // Workspace map (float offsets; 25,165,824-float budget).
  // Phase 1: c1h [0, 8.39M) halves=16.78M | c2h [16.78M, 20.97M)
  // weights [20.97M..): W2h/W2l/W3h/W3l/WTh/WTl/WeTh/WeTl
  // Phase 2 (c1h dead after conv2m): node [4.19M, 6.29M) gx [6.29M, 8.39M)
  //   Abf [8.39M, 9.44M) A2bf [9.44M, 10.49M) mo [10.49M, ..)
  unsigned short* c1h = (unsigned short*)(ws);
  unsigned short* c2h = (unsigned short*)(ws + 16777216);
  unsigned short* W2h = (unsigned short*)(ws + 20971520);
  unsigned short* W2l = (unsigned short*)(ws + 20980736);
  unsigned short* W3h = (unsigned short*)(ws + 20989952);
  unsigned short* W3l = (unsigned short*)(ws + 21026816);
  unsigned short* WTh = (unsigned short*)(ws + 21063680);
  unsigned short* WTl = (unsigned short*)(ws + 21069824);
  unsigned short* WeTh = (unsigned short*)(ws + 21075968);
  unsigned short* WeTl = (unsigned short*)(ws + 21080064);
  float* node = ws + 4194304;
  float* gx   = ws + 6291456;
  unsigned short* Abf  = (unsigned short*)(ws + 8388608);
  unsigned short* A2bf = (unsigned short*)(ws + 9437184);
  float* mo   = ws + 10485760;
  float* out  = (float*)d_out;

  wprep_k <<<440, 256, 0, stream>>>(Wc2, Wc3, Wh, We, W2h, W2l, W3h, W3l, WTh, WTl, WeTh, WeTl);
  conv1_k <<<512, 256, 0, stream>>>(frames, Wc1, bc1, c1h);
  conv2m_k<<<512, 256, 0, stream>>>(c1h, W2h, W2l, bc2, c2h);
  conv3e_k<<<512, 256, 0, stream>>>(c2h, W3h, W3l, bc3, WeTh, WeTl, be, node);
  prep_k  <<<512, 256, 0, stream>>>(adj, node, Wx, Abf, A2bf, gx);
  seq2_k  <<<8,  1024, 0, stream>>>(Abf, A2bf, gx, h0, WTh, WTl, bg, tau, Ap, mo, out);
  dec_k   <<<512, 128, 0, stream>>>(mo, Wd1, bd1, Wd2, bd2, Wd3, bd3, out);
}